// Round 7
// baseline (5090.104 us; speedup 1.0000x reference)
//
#include <hip/hip_runtime.h>
#include <hip/hip_bf16.h>

#define NN 50000
#define NE 1000000
#define NG 256
#define NL 6
#define NB_SCAN 196   // ceil(NN/256)
#define EB 128        // edges per block in k_edge2

__device__ __forceinline__ float siluf(float v){ return v / (1.0f + __expf(-v)); }

// ---- degree counts ----
__global__ void k_degrees(const int* __restrict__ ei, int* __restrict__ cnt_dst,
                          int* __restrict__ cnt_src){
  int e = blockIdx.x*256 + threadIdx.x;
  if (e<NE){
    atomicAdd(&cnt_dst[ei[NE+e]], 1);
    atomicAdd(&cnt_src[ei[e]], 1);
  }
}

// ---- hierarchical scan ----
__global__ void k_scan1(const int* __restrict__ cnt, int* __restrict__ roff,
                        int* __restrict__ bsum){
  __shared__ int sd[256];
  int t=threadIdx.x; int i=blockIdx.x*256+t;
  int v=(i<NN)?cnt[i]:0;
  sd[t]=v; __syncthreads();
  #pragma unroll
  for(int off=1;off<256;off<<=1){
    int xv=(t>=off)?sd[t-off]:0; __syncthreads();
    sd[t]+=xv; __syncthreads();
  }
  if(i<NN) roff[i]=sd[t]-v;
  if(t==255) bsum[blockIdx.x]=sd[t];
}
__global__ void k_scan2(const int* __restrict__ bsum, int* __restrict__ bbase,
                        int* __restrict__ roff){
  __shared__ int sd[256];
  int t=threadIdx.x;
  int v=(t<NB_SCAN)?bsum[t]:0;
  sd[t]=v; __syncthreads();
  #pragma unroll
  for(int off=1;off<256;off<<=1){
    int xv=(t>=off)?sd[t-off]:0; __syncthreads();
    sd[t]+=xv; __syncthreads();
  }
  if(t<NB_SCAN) bbase[t]=sd[t]-v;
  if(t==255) roff[NN]=sd[t];
}
__global__ void k_scan3(int* __restrict__ roff, const int* __restrict__ bbase){
  int i=blockIdx.x*256+threadIdx.x;
  if(i<NN) roff[i]+=bbase[blockIdx.x];
}

// ---- scatter-fill: dlist = edge ids in dst-sorted order; slist = dst-sorted POSITIONS per src ----
__global__ void k_fill(const int* __restrict__ ei,
                       const int* __restrict__ roff_dst, const int* __restrict__ roff_src,
                       int* __restrict__ cur_dst, int* __restrict__ cur_src,
                       int* __restrict__ dlist, int* __restrict__ slist){
  int e = blockIdx.x*256 + threadIdx.x;
  if (e<NE){
    int d = ei[NE+e];
    int pd = roff_dst[d] + atomicAdd(&cur_dst[d],1);
    dlist[pd] = e;
    int s = ei[e];
    int ps = roff_src[s] + atomicAdd(&cur_src[s],1);
    slist[ps] = pd;
  }
}

// ---- one-time gather into dst-sorted order ----
__global__ void k_gather(const int* __restrict__ ei, const float* __restrict__ ef,
                         const int* __restrict__ dlist,
                         int2* __restrict__ sd_s, float* __restrict__ ef_s){
  int p = blockIdx.x*256 + threadIdx.x;
  if (p<NE){
    int e = dlist[p];
    sd_s[p] = make_int2(ei[e], ei[NE+e]);
    const float4* src = (const float4*)(ef + (size_t)e*16);
    float4* dst = (float4*)(ef_s + (size_t)p*16);
    dst[0]=src[0]; dst[1]=src[1]; dst[2]=src[2]; dst[3]=src[3];
  }
}

// ---- init coords + 1/max(indeg,1) ----
__global__ void k_prep(const float* __restrict__ coords,
                       const int* __restrict__ cnt,
                       float* __restrict__ x, float* __restrict__ cntinv){
  int n = blockIdx.x*256+threadIdx.x;
  if (n<NN){
    x[n*3+0]=coords[n*3+0];
    x[n*3+1]=coords[n*3+1];
    x[n*3+2]=coords[n*3+2];
    cntinv[n]=1.0f/fmaxf((float)cnt[n],1.0f);
  }
}

// ==== tiled encoder ====
__global__ void __launch_bounds__(256)
k_encoder(const float* __restrict__ nf,
          const float* __restrict__ w1, const float* __restrict__ b1,
          const float* __restrict__ w2, const float* __restrict__ b2,
          float* __restrict__ h){
  __shared__ float in1[32][17];
  __shared__ float t1[32][129];
  __shared__ float wt[16][136];
  int tid=threadIdx.x;
  int g0=blockIdx.x*32;
  int ty=tid>>4, tx=tid&15;
  int n0=ty*2, n1=ty*2+1;
  { int n=tid>>3, c=(tid&7)*2;
    int gn=g0+n; if(gn>=NN) gn=NN-1;
    float2 v=*(const float2*)(nf+(size_t)gn*16+c);
    in1[n][c]=v.x; in1[n][c+1]=v.y; }
  { int c=tx*8;
    const float* src=w1+(size_t)ty*128+c;
    *(float4*)&wt[ty][c]  =*(const float4*)src;
    *(float4*)&wt[ty][c+4]=*(const float4*)(src+4); }
  __syncthreads();
  float4 a00,a01,a10,a11;
  a00=*(const float4*)(b1+tx*8); a01=*(const float4*)(b1+tx*8+4);
  a10=a00; a11=a01;
  #pragma unroll
  for(int k=0;k<16;k++){
    float m0=in1[n0][k], m1=in1[n1][k];
    float4 wa=*(float4*)&wt[k][tx*8], wb=*(float4*)&wt[k][tx*8+4];
    a00.x+=m0*wa.x; a00.y+=m0*wa.y; a00.z+=m0*wa.z; a00.w+=m0*wa.w;
    a01.x+=m0*wb.x; a01.y+=m0*wb.y; a01.z+=m0*wb.z; a01.w+=m0*wb.w;
    a10.x+=m1*wa.x; a10.y+=m1*wa.y; a10.z+=m1*wa.z; a10.w+=m1*wa.w;
    a11.x+=m1*wb.x; a11.y+=m1*wb.y; a11.z+=m1*wb.z; a11.w+=m1*wb.w;
  }
  int c8=tx*8;
  t1[n0][c8+0]=siluf(a00.x); t1[n0][c8+1]=siluf(a00.y); t1[n0][c8+2]=siluf(a00.z); t1[n0][c8+3]=siluf(a00.w);
  t1[n0][c8+4]=siluf(a01.x); t1[n0][c8+5]=siluf(a01.y); t1[n0][c8+6]=siluf(a01.z); t1[n0][c8+7]=siluf(a01.w);
  t1[n1][c8+0]=siluf(a10.x); t1[n1][c8+1]=siluf(a10.y); t1[n1][c8+2]=siluf(a10.z); t1[n1][c8+3]=siluf(a10.w);
  t1[n1][c8+4]=siluf(a11.x); t1[n1][c8+5]=siluf(a11.y); t1[n1][c8+6]=siluf(a11.z); t1[n1][c8+7]=siluf(a11.w);
  __syncthreads();
  a00=*(const float4*)(b2+c8); a01=*(const float4*)(b2+c8+4);
  a10=a00; a11=a01;
  for(int kt=0;kt<8;kt++){
    { const float* src=w2+(size_t)(kt*16+ty)*128+c8;
      *(float4*)&wt[ty][c8]  =*(const float4*)src;
      *(float4*)&wt[ty][c8+4]=*(const float4*)(src+4); }
    __syncthreads();
    #pragma unroll
    for(int kk=0;kk<16;kk++){
      int k=kt*16+kk;
      float m0=t1[n0][k], m1=t1[n1][k];
      float4 wa=*(float4*)&wt[kk][c8], wb=*(float4*)&wt[kk][c8+4];
      a00.x+=m0*wa.x; a00.y+=m0*wa.y; a00.z+=m0*wa.z; a00.w+=m0*wa.w;
      a01.x+=m0*wb.x; a01.y+=m0*wb.y; a01.z+=m0*wb.z; a01.w+=m0*wb.w;
      a10.x+=m1*wa.x; a10.y+=m1*wa.y; a10.z+=m1*wa.z; a10.w+=m1*wa.w;
      a11.x+=m1*wb.x; a11.y+=m1*wb.y; a11.z+=m1*wb.z; a11.w+=m1*wb.w;
    }
    __syncthreads();
  }
  int gn0=g0+n0, gn1=g0+n1;
  if(gn0<NN){ *(float4*)(h+(size_t)gn0*128+c8)=a00; *(float4*)(h+(size_t)gn0*128+c8+4)=a01; }
  if(gn1<NN){ *(float4*)(h+(size_t)gn1*128+c8)=a10; *(float4*)(h+(size_t)gn1*128+c8+4)=a11; }
}

// ==== standalone k_pre (layer 0 only) ====
__global__ void __launch_bounds__(256)
k_pre(const float* __restrict__ h,
      const float* __restrict__ w1, const float* __restrict__ b1,
      float* __restrict__ pa, float* __restrict__ pb){
  __shared__ float hs[32][129];
  __shared__ float wt[16][136];
  int tid=threadIdx.x;
  int g0=blockIdx.x*32;
  int ty=tid>>4, tx=tid&15;
  int n0=ty*2, n1=ty*2+1;
  { int n=tid>>3, c0=(tid&7)*16;
    int gn=g0+n; if(gn>=NN) gn=NN-1;
    const float* src=h+(size_t)gn*128+c0;
    #pragma unroll
    for(int q=0;q<4;q++){
      float4 v=*(const float4*)(src+q*4);
      hs[n][c0+q*4]=v.x; hs[n][c0+q*4+1]=v.y; hs[n][c0+q*4+2]=v.z; hs[n][c0+q*4+3]=v.w;
    } }
  int c8=tx*8;
  float4 a00,a01,a10,a11;
  if(tx<8){ a00=*(const float4*)(b1+c8); a01=*(const float4*)(b1+c8+4); }
  else    { a00=make_float4(0,0,0,0); a01=a00; }
  a10=a00; a11=a01;
  for(int kt=0;kt<8;kt++){
    { int grow=(tx<8)?(kt*16+ty):(128+kt*16+ty);
      int gcol=(tx&7)*8;
      const float* src=w1+(size_t)grow*64+gcol;
      *(float4*)&wt[ty][c8]  =*(const float4*)src;
      *(float4*)&wt[ty][c8+4]=*(const float4*)(src+4); }
    __syncthreads();
    #pragma unroll
    for(int kk=0;kk<16;kk++){
      int k=kt*16+kk;
      float m0=hs[n0][k], m1=hs[n1][k];
      float4 wa=*(float4*)&wt[kk][c8], wb=*(float4*)&wt[kk][c8+4];
      a00.x+=m0*wa.x; a00.y+=m0*wa.y; a00.z+=m0*wa.z; a00.w+=m0*wa.w;
      a01.x+=m0*wb.x; a01.y+=m0*wb.y; a01.z+=m0*wb.z; a01.w+=m0*wb.w;
      a10.x+=m1*wa.x; a10.y+=m1*wa.y; a10.z+=m1*wa.z; a10.w+=m1*wa.w;
      a11.x+=m1*wb.x; a11.y+=m1*wb.y; a11.z+=m1*wb.z; a11.w+=m1*wb.w;
    }
    __syncthreads();
  }
  int gn0=g0+n0, gn1=g0+n1;
  float* base0 = (tx<8)? (pa+(size_t)gn0*64+c8) : (pb+(size_t)gn0*64+(c8-64));
  float* base1 = (tx<8)? (pa+(size_t)gn1*64+c8) : (pb+(size_t)gn1*64+(c8-64));
  if(gn0<NN){ *(float4*)base0=a00; *(float4*)(base0+4)=a01; }
  if(gn1<NN){ *(float4*)base1=a10; *(float4*)(base1+4)=a11; }
}

// ==== fused edge kernel ====
__global__ void __launch_bounds__(256,4)
k_edge2(const int2* __restrict__ sd, const float* __restrict__ efs,
        const float* __restrict__ x,
        const float* __restrict__ pa, const float* __restrict__ pb,
        const int* __restrict__ roff_dst,
        const float* __restrict__ w1,
        const float* __restrict__ w2, const float* __restrict__ b2,
        const float* __restrict__ xw1, const float* __restrict__ xb1,
        const float* __restrict__ xw2, const float* __restrict__ xb2,
        float* __restrict__ agg, float* __restrict__ wvs){
  __shared__ float tls[EB*65];
  __shared__ float wvp[EB];
  int bid = blockIdx.x;
  int nb = (bid&7)*((int)gridDim.x>>3) + (bid>>3);
  int p0 = nb*EB;
  if (p0 >= NE) return;
  int tid = threadIdx.x;
  int wl = tid>>6, lane = tid&63;
  int eidx = (wl&1)*64 + lane;
  int c0 = __builtin_amdgcn_readfirstlane((wl>>1)*32);
  int p  = p0 + eidx;
  bool valid = (p < NE);
  float acc[32];
  float part = 0.f;
  if (valid){
    int2 sdp = sd[p];
    int s = sdp.x, d = sdp.y;
    float dx = x[s*3+0]-x[d*3+0];
    float dy = x[s*3+1]-x[d*3+1];
    float dz = x[s*3+2]-x[d*3+2];
    float sq = dx*dx+dy*dy+dz*dz;
    const float4* pa4 = (const float4*)(pa + (size_t)s*64 + c0);
    const float4* pb4 = (const float4*)(pb + (size_t)d*64 + c0);
    #pragma unroll
    for(int q=0;q<8;q++){
      float4 A=pa4[q], B=pb4[q];
      acc[q*4+0]=A.x+B.x; acc[q*4+1]=A.y+B.y; acc[q*4+2]=A.z+B.z; acc[q*4+3]=A.w+B.w;
    }
    { const float* wr = w1 + 256*64 + c0;
      #pragma unroll
      for(int j=0;j<32;j++) acc[j] += sq*wr[j]; }
    { const float4* efp=(const float4*)(efs+(size_t)p*16);
      #pragma unroll
      for(int k4=0;k4<4;k4++){
        float4 m4=efp[k4];
        float mv[4]={m4.x,m4.y,m4.z,m4.w};
        #pragma unroll
        for(int kk=0;kk<4;kk++){
          const float* wr = w1 + (257+k4*4+kk)*64 + c0;
          float m=mv[kk];
          #pragma unroll
          for(int j=0;j<32;j++) acc[j]+=m*wr[j];
        }
      } }
    #pragma unroll
    for(int j=0;j<32;j++) tls[eidx*65 + c0 + j] = siluf(acc[j]);
  }
  __syncthreads();                 // t complete
  if (valid){
    #pragma unroll
    for(int j=0;j<32;j++) acc[j]=b2[c0+j];
    #pragma unroll 4
    for(int k=0;k<64;k++){
      float m = tls[eidx*65+k];
      const float* wr = w2 + k*64 + c0;
      #pragma unroll
      for(int j=0;j<32;j++) acc[j] += m*wr[j];
    }
    #pragma unroll
    for(int j=0;j<32;j++) acc[j]=siluf(acc[j]);   // msg half
  }
  __syncthreads();                 // all t reads done
  if (valid){
    #pragma unroll
    for(int j=0;j<32;j++) tls[eidx*65+c0+j] = acc[j];  // msg into LDS
  }
  __syncthreads();                 // msg complete
  if (valid){
    #pragma unroll
    for(int j=0;j<32;j++) acc[j]=xb1[c0+j];
    #pragma unroll 4
    for(int k=0;k<64;k++){
      float m = tls[eidx*65+k];
      const float* wr = xw1 + k*64 + c0;
      #pragma unroll
      for(int j=0;j<32;j++) acc[j]+=m*wr[j];
    }
    const float* xw2c = xw2 + c0;
    #pragma unroll
    for(int j=0;j<32;j++) part += siluf(acc[j])*xw2c[j];
    if ((wl>>1)==0) wvp[eidx]=part;
  }
  __syncthreads();                 // wvp + msg final
  int pend = (p0+EB < NE) ? (p0+EB) : NE;
  if (valid && (wl>>1)==1) wvs[p] = wvp[eidx] + part + xb2[0];
  // fused segmented reduction over dst; exclusive segments use plain stores
  int dfirst = sd[p0].y;
  int dlast  = sd[pend-1].y;
  int j = tid&63, slot = tid>>6;
  for (int n=dfirst+slot; n<=dlast; n+=4){
    int rs0 = roff_dst[n], re0 = roff_dst[n+1];
    int rs = (rs0 > p0)   ? rs0 : p0;
    int re = (re0 < pend) ? re0 : pend;
    rs -= p0; re -= p0;
    if (re > rs){
      float sum=0.f;
      for (int r=rs; r<re; r++) sum += tls[r*65+j];
      if (rs0 >= p0 && re0 <= pend) agg[(size_t)n*64+j] = sum;      // exclusive
      else                          atomicAdd(&agg[(size_t)n*64+j], sum);
    }
  }
}

// ---- phase C: 16 lanes per src node ----
__global__ void k_coordC(const int2* __restrict__ sd,
                         const int* __restrict__ roff_src, const int* __restrict__ slist,
                         const float* __restrict__ wvs, const float* __restrict__ x,
                         float* __restrict__ cacc){
  int tid=threadIdx.x;
  int grp=tid>>4, sub=tid&15;
  int n = blockIdx.x*16 + grp;
  if (n >= NN) return;
  int s = roff_src[n], e2 = roff_src[n+1];
  float xs0=x[n*3+0], xs1=x[n*3+1], xs2=x[n*3+2];
  float a0=0.f, a1=0.f, a2=0.f;
  for (int p=s+sub; p<e2; p+=16){
    int q = slist[p];
    float w = wvs[q];
    int d = sd[q].y;
    a0 += (xs0 - x[d*3+0])*w;
    a1 += (xs1 - x[d*3+1])*w;
    a2 += (xs2 - x[d*3+2])*w;
  }
  #pragma unroll
  for(int off=1; off<16; off<<=1){
    a0 += __shfl_xor(a0, off);
    a1 += __shfl_xor(a1, off);
    a2 += __shfl_xor(a2, off);
  }
  if (sub==0){
    cacc[n*3+0]=a0; cacc[n*3+1]=a1; cacc[n*3+2]=a2;
  }
}

// ==== tiled k_node + fused next-layer pre ====
__global__ void __launch_bounds__(256)
k_node(const float* __restrict__ agg, const float* __restrict__ cacc,
       const float* __restrict__ cntinv,
       const float* __restrict__ hw1, const float* __restrict__ hb1,
       const float* __restrict__ hw2, const float* __restrict__ hb2,
       const float* __restrict__ lng, const float* __restrict__ lnb,
       float* __restrict__ h, float* __restrict__ x,
       const float* __restrict__ pw1, const float* __restrict__ pb1,
       float* __restrict__ pa, float* __restrict__ pb, int do_pre){
  __shared__ float cat[32][193];
  __shared__ float t1[32][129];
  __shared__ float wt[16][136];
  __shared__ float psA[32][8], psB[32][8];
  __shared__ float mu_s[32], rs_s[32];
  int tid=threadIdx.x;
  int g0=blockIdx.x*32;
  int ty=tid>>4, tx=tid&15;
  int n0=ty*2, n1=ty*2+1;
  int c8=tx*8;
  { int n=tid>>3, c0=(tid&7)*16;
    int gn=g0+n; if(gn>=NN) gn=NN-1;
    float ci = cntinv[gn];
    const float* src=h+(size_t)gn*128+c0;
    #pragma unroll
    for(int q=0;q<4;q++){
      float4 v=*(const float4*)(src+q*4);
      cat[n][c0+q*4]=v.x; cat[n][c0+q*4+1]=v.y; cat[n][c0+q*4+2]=v.z; cat[n][c0+q*4+3]=v.w;
    }
    int ca=(tid&7)*8;
    const float* srca=agg+(size_t)gn*64+ca;
    #pragma unroll
    for(int q=0;q<2;q++){
      float4 v=*(const float4*)(srca+q*4);
      cat[n][128+ca+q*4]=v.x*ci; cat[n][128+ca+q*4+1]=v.y*ci;
      cat[n][128+ca+q*4+2]=v.z*ci; cat[n][128+ca+q*4+3]=v.w*ci;
    } }
  float4 a00=*(const float4*)(hb1+c8), a01=*(const float4*)(hb1+c8+4);
  float4 a10=a00, a11=a01;
  for(int kt=0;kt<12;kt++){
    { const float* src=hw1+(size_t)(kt*16+ty)*128+c8;
      *(float4*)&wt[ty][c8]  =*(const float4*)src;
      *(float4*)&wt[ty][c8+4]=*(const float4*)(src+4); }
    __syncthreads();
    #pragma unroll
    for(int kk=0;kk<16;kk++){
      int k=kt*16+kk;
      float m0=cat[n0][k], m1=cat[n1][k];
      float4 wa=*(float4*)&wt[kk][c8], wb=*(float4*)&wt[kk][c8+4];
      a00.x+=m0*wa.x; a00.y+=m0*wa.y; a00.z+=m0*wa.z; a00.w+=m0*wa.w;
      a01.x+=m0*wb.x; a01.y+=m0*wb.y; a01.z+=m0*wb.z; a01.w+=m0*wb.w;
      a10.x+=m1*wa.x; a10.y+=m1*wa.y; a10.z+=m1*wa.z; a10.w+=m1*wa.w;
      a11.x+=m1*wb.x; a11.y+=m1*wb.y; a11.z+=m1*wb.z; a11.w+=m1*wb.w;
    }
    __syncthreads();
  }
  t1[n0][c8+0]=siluf(a00.x); t1[n0][c8+1]=siluf(a00.y); t1[n0][c8+2]=siluf(a00.z); t1[n0][c8+3]=siluf(a00.w);
  t1[n0][c8+4]=siluf(a01.x); t1[n0][c8+5]=siluf(a01.y); t1[n0][c8+6]=siluf(a01.z); t1[n0][c8+7]=siluf(a01.w);
  t1[n1][c8+0]=siluf(a10.x); t1[n1][c8+1]=siluf(a10.y); t1[n1][c8+2]=siluf(a10.z); t1[n1][c8+3]=siluf(a10.w);
  t1[n1][c8+4]=siluf(a11.x); t1[n1][c8+5]=siluf(a11.y); t1[n1][c8+6]=siluf(a11.z); t1[n1][c8+7]=siluf(a11.w);
  __syncthreads();
  a00=*(const float4*)(hb2+c8); a01=*(const float4*)(hb2+c8+4);
  a10=a00; a11=a01;
  for(int kt=0;kt<8;kt++){
    { const float* src=hw2+(size_t)(kt*16+ty)*128+c8;
      *(float4*)&wt[ty][c8]  =*(const float4*)src;
      *(float4*)&wt[ty][c8+4]=*(const float4*)(src+4); }
    __syncthreads();
    #pragma unroll
    for(int kk=0;kk<16;kk++){
      int k=kt*16+kk;
      float m0=t1[n0][k], m1=t1[n1][k];
      float4 wa=*(float4*)&wt[kk][c8], wb=*(float4*)&wt[kk][c8+4];
      a00.x+=m0*wa.x; a00.y+=m0*wa.y; a00.z+=m0*wa.z; a00.w+=m0*wa.w;
      a01.x+=m0*wb.x; a01.y+=m0*wb.y; a01.z+=m0*wb.z; a01.w+=m0*wb.w;
      a10.x+=m1*wa.x; a10.y+=m1*wa.y; a10.z+=m1*wa.z; a10.w+=m1*wa.w;
      a11.x+=m1*wb.x; a11.y+=m1*wb.y; a11.z+=m1*wb.z; a11.w+=m1*wb.w;
    }
    __syncthreads();
  }
  cat[n0][c8+0]+=a00.x; cat[n0][c8+1]+=a00.y; cat[n0][c8+2]+=a00.z; cat[n0][c8+3]+=a00.w;
  cat[n0][c8+4]+=a01.x; cat[n0][c8+5]+=a01.y; cat[n0][c8+6]+=a01.z; cat[n0][c8+7]+=a01.w;
  cat[n1][c8+0]+=a10.x; cat[n1][c8+1]+=a10.y; cat[n1][c8+2]+=a10.z; cat[n1][c8+3]+=a10.w;
  cat[n1][c8+4]+=a11.x; cat[n1][c8+5]+=a11.y; cat[n1][c8+6]+=a11.z; cat[n1][c8+7]+=a11.w;
  __syncthreads();
  { int rid=tid>>3, sub=tid&7;
    float sm=0.f, ss=0.f;
    #pragma unroll
    for(int i=0;i<16;i++){ float v=cat[rid][sub*16+i]; sm+=v; ss+=v*v; }
    psA[rid][sub]=sm; psB[rid][sub]=ss; }
  __syncthreads();
  { int rid=tid>>3, sub=tid&7;
    if(sub==0){
      float sm=0.f, ss=0.f;
      #pragma unroll
      for(int i=0;i<8;i++){ sm+=psA[rid][i]; ss+=psB[rid][i]; }
      float mu=sm*(1.0f/128.0f);
      float var=ss*(1.0f/128.0f)-mu*mu;
      mu_s[rid]=mu; rs_s[rid]=rsqrtf(fmaxf(var,0.0f)+1e-5f);
    } }
  __syncthreads();
  // normalize INTO cat, then store h from cat
  { int rid=tid>>3, sub=tid&7;
    int gn=g0+rid;
    float mu=mu_s[rid], rs=rs_s[rid];
    int c0=sub*16;
    #pragma unroll
    for(int q=0;q<4;q++){
      float4 g4=*(const float4*)(lng+c0+q*4);
      float4 b4=*(const float4*)(lnb+c0+q*4);
      float4 o;
      o.x=(cat[rid][c0+q*4+0]-mu)*rs*g4.x+b4.x;
      o.y=(cat[rid][c0+q*4+1]-mu)*rs*g4.y+b4.y;
      o.z=(cat[rid][c0+q*4+2]-mu)*rs*g4.z+b4.z;
      o.w=(cat[rid][c0+q*4+3]-mu)*rs*g4.w+b4.w;
      cat[rid][c0+q*4+0]=o.x; cat[rid][c0+q*4+1]=o.y;
      cat[rid][c0+q*4+2]=o.z; cat[rid][c0+q*4+3]=o.w;
      if(gn<NN) *(float4*)(h+(size_t)gn*128+c0+q*4)=o;
    } }
  if(tid<32){
    int gn=g0+tid;
    if(gn<NN){
      float ci=cntinv[gn];
      x[gn*3+0]+=cacc[gn*3+0]*ci;
      x[gn*3+1]+=cacc[gn*3+1]*ci;
      x[gn*3+2]+=cacc[gn*3+2]*ci;
    }
  }
  if(do_pre){
    __syncthreads();   // cat now holds normalized h
    float4 p00,p01,p10,p11;
    if(tx<8){ p00=*(const float4*)(pb1+c8); p01=*(const float4*)(pb1+c8+4); }
    else    { p00=make_float4(0,0,0,0); p01=p00; }
    p10=p00; p11=p01;
    for(int kt=0;kt<8;kt++){
      { int grow=(tx<8)?(kt*16+ty):(128+kt*16+ty);
        int gcol=(tx&7)*8;
        const float* src=pw1+(size_t)grow*64+gcol;
        *(float4*)&wt[ty][c8]  =*(const float4*)src;
        *(float4*)&wt[ty][c8+4]=*(const float4*)(src+4); }
      __syncthreads();
      #pragma unroll
      for(int kk=0;kk<16;kk++){
        int k=kt*16+kk;
        float m0=cat[n0][k], m1=cat[n1][k];
        float4 wa=*(float4*)&wt[kk][c8], wb=*(float4*)&wt[kk][c8+4];
        p00.x+=m0*wa.x; p00.y+=m0*wa.y; p00.z+=m0*wa.z; p00.w+=m0*wa.w;
        p01.x+=m0*wb.x; p01.y+=m0*wb.y; p01.z+=m0*wb.z; p01.w+=m0*wb.w;
        p10.x+=m1*wa.x; p10.y+=m1*wa.y; p10.z+=m1*wa.z; p10.w+=m1*wa.w;
        p11.x+=m1*wb.x; p11.y+=m1*wb.y; p11.z+=m1*wb.z; p11.w+=m1*wb.w;
      }
      __syncthreads();
    }
    int gn0=g0+n0, gn1=g0+n1;
    float* base0 = (tx<8)? (pa+(size_t)gn0*64+c8) : (pb+(size_t)gn0*64+(c8-64));
    float* base1 = (tx<8)? (pa+(size_t)gn1*64+c8) : (pb+(size_t)gn1*64+(c8-64));
    if(gn0<NN){ *(float4*)base0=p00; *(float4*)(base0+4)=p01; }
    if(gn1<NN){ *(float4*)base1=p10; *(float4*)(base1+4)=p11; }
  }
}

// ---- readout ----
__device__ __forceinline__ int lowerb(const int* a, int n, int v){
  int lo=0, hi=n;
  while(lo<hi){ int mid=(lo+hi)>>1; if(a[mid]<v) lo=mid+1; else hi=mid; }
  return lo;
}

__global__ void k_readout(const int* __restrict__ batch, const float* __restrict__ h,
                          const float* __restrict__ w1, const float* __restrict__ b1,
                          const float* __restrict__ w2, const float* __restrict__ b2,
                          const float* __restrict__ w3, const float* __restrict__ b3,
                          float* __restrict__ out){
  int g = blockIdx.x;
  int wl = threadIdx.x>>6, lane = threadIdx.x&63;
  __shared__ float part[4][128];
  __shared__ float gh[128];
  __shared__ float r1[128];
  __shared__ float r2[64];
  int start = lowerb(batch, NN, g);
  int end   = lowerb(batch, NN, g+1);
  float s0=0.f, s1=0.f;
  for(int n=start+wl; n<end; n+=4){
    s0 += h[(size_t)n*128+2*lane];
    s1 += h[(size_t)n*128+2*lane+1];
  }
  part[wl][2*lane]=s0; part[wl][2*lane+1]=s1;
  __syncthreads();
  float ci = 1.0f/fmaxf((float)(end-start),1.0f);
  if(wl==0){
    gh[2*lane]   = (part[0][2*lane]+part[1][2*lane]+part[2][2*lane]+part[3][2*lane])*ci;
    gh[2*lane+1] = (part[0][2*lane+1]+part[1][2*lane+1]+part[2][2*lane+1]+part[3][2*lane+1])*ci;
  }
  __syncthreads();
  if(wl==0){
    float a0=b1[2*lane], a1=b1[2*lane+1];
    for(int k=0;k<128;k++){
      float m=gh[k];
      float2 w=((const float2*)(w1+k*128))[lane];
      a0+=m*w.x; a1+=m*w.y;
    }
    r1[2*lane]=siluf(a0); r1[2*lane+1]=siluf(a1);
  }
  __syncthreads();
  if(wl==0){
    float b=b2[lane];
    for(int k=0;k<128;k++) b += r1[k]*w2[k*64+lane];
    r2[lane]=siluf(b);
  }
  __syncthreads();
  if(wl==0 && lane<2){
    float o=b3[lane];
    for(int k=0;k<64;k++) o += r2[k]*w3[k*2+lane];
    out[g*2+lane]=o;
  }
}

extern "C" void kernel_launch(void* const* d_in, const int* in_sizes, int n_in,
                              void* d_out, int out_size, void* d_ws, size_t ws_size,
                              hipStream_t stream){
  const float* nf     = (const float*)d_in[0];
  const float* coords = (const float*)d_in[1];
  const int*   ei     = (const int*)d_in[2];
  const float* ef     = (const float*)d_in[3];
  const int*   batch  = (const int*)d_in[4];

  const float* enc_w1 = (const float*)d_in[5];
  const float* enc_b1 = (const float*)d_in[6];
  const float* enc_w2 = (const float*)d_in[7];
  const float* enc_b2 = (const float*)d_in[8];
  const float* pe_w1  = (const float*)d_in[9];
  const float* pe_b1  = (const float*)d_in[10];
  const float* pe_w2  = (const float*)d_in[11];
  const float* pe_b2  = (const float*)d_in[12];
  const float* ph_w1  = (const float*)d_in[13];
  const float* ph_b1  = (const float*)d_in[14];
  const float* ph_w2  = (const float*)d_in[15];
  const float* ph_b2  = (const float*)d_in[16];
  const float* px_w1  = (const float*)d_in[17];
  const float* px_b1  = (const float*)d_in[18];
  const float* px_w2  = (const float*)d_in[19];
  const float* px_b2  = (const float*)d_in[20];
  const float* ln_g   = (const float*)d_in[21];
  const float* ln_b   = (const float*)d_in[22];
  const float* ro_w1  = (const float*)d_in[23];
  const float* ro_b1  = (const float*)d_in[24];
  const float* ro_w2  = (const float*)d_in[25];
  const float* ro_b2  = (const float*)d_in[26];
  const float* ro_w3  = (const float*)d_in[27];
  const float* ro_b3  = (const float*)d_in[28];

  char* wsb = (char*)d_ws;
  size_t off = 0;
  auto alloc_f = [&](size_t nfl)->float*{ float* p=(float*)(wsb+off); off+=nfl*4; return p; };
  auto alloc_i = [&](size_t nin)->int*  { int*   p=(int*)(wsb+off);   off+=nin*4; return p; };

  float* h      = alloc_f((size_t)NN*128);
  float* x      = alloc_f((size_t)NN*3);
  float* agg    = alloc_f((size_t)NN*64);
  float* cacc   = alloc_f((size_t)NN*3);
  float* cntinv = alloc_f(NN);
  float* pa     = alloc_f((size_t)NN*64);
  float* pb     = alloc_f((size_t)NN*64);
  float* wvs    = alloc_f(NE);
  float* ef_s   = alloc_f((size_t)NE*16);
  int2*  sd_s   = (int2*)alloc_i((size_t)NE*2);
  int* roff_dst = alloc_i(NN+1);
  int* roff_src = alloc_i(NN+1);
  int* dlist    = alloc_i(NE);
  int* slist    = alloc_i(NE);
  int* bsum     = alloc_i(256);
  int* bbase    = alloc_i(256);
  int* cnt_dst  = alloc_i(NN);   // cnt_dst..cur_src contiguous -> one memset
  int* cnt_src  = alloc_i(NN);
  int* cur_dst  = alloc_i(NN);
  int* cur_src  = alloc_i(NN);

  hipMemsetAsync(cnt_dst, 0, (size_t)4*NN*sizeof(int), stream);
  k_degrees<<<(NE+255)/256,256,0,stream>>>(ei, cnt_dst, cnt_src);
  k_scan1<<<NB_SCAN,256,0,stream>>>(cnt_dst, roff_dst, bsum);
  k_scan2<<<1,256,0,stream>>>(bsum, bbase, roff_dst);
  k_scan3<<<NB_SCAN,256,0,stream>>>(roff_dst, bbase);
  k_scan1<<<NB_SCAN,256,0,stream>>>(cnt_src, roff_src, bsum);
  k_scan2<<<1,256,0,stream>>>(bsum, bbase, roff_src);
  k_scan3<<<NB_SCAN,256,0,stream>>>(roff_src, bbase);
  k_fill<<<(NE+255)/256,256,0,stream>>>(ei, roff_dst, roff_src, cur_dst, cur_src, dlist, slist);
  k_gather<<<(NE+255)/256,256,0,stream>>>(ei, ef, dlist, sd_s, ef_s);
  k_prep<<<(NN+255)/256,256,0,stream>>>(coords, cnt_dst, x, cntinv);
  k_encoder<<<(NN+31)/32,256,0,stream>>>(nf, enc_w1, enc_b1, enc_w2, enc_b2, h);
  k_pre<<<(NN+31)/32,256,0,stream>>>(h, pe_w1, pe_b1, pa, pb);   // layer 0

  int G  = (NE+EB-1)/EB;
  int G8 = ((G+7)/8)*8;

  for(int l=0;l<NL;l++){
    hipMemsetAsync(agg, 0, (size_t)NN*64*sizeof(float), stream);
    k_edge2<<<G8,256,0,stream>>>(sd_s, ef_s, x, pa, pb, roff_dst,
        pe_w1+(size_t)l*273*64,
        pe_w2+(size_t)l*64*64, pe_b2+l*64,
        px_w1+(size_t)l*64*64, px_b1+l*64,
        px_w2+l*64, px_b2+l,
        agg, wvs);
    k_coordC<<<(NN+15)/16,256,0,stream>>>(sd_s, roff_src, slist, wvs, x, cacc);
    int nl2 = l+1;
    int do_pre = (nl2 < NL) ? 1 : 0;
    const float* pw1n = pe_w1 + (size_t)(do_pre? nl2:0)*273*64;
    const float* pb1n = pe_b1 + (size_t)(do_pre? nl2:0)*64;
    k_node<<<(NN+31)/32,256,0,stream>>>(agg, cacc, cntinv,
        ph_w1+(size_t)l*192*128, ph_b1+l*128,
        ph_w2+(size_t)l*128*128, ph_b2+l*128,
        ln_g+l*128, ln_b+l*128, h, x,
        pw1n, pb1n, pa, pb, do_pre);
  }

  k_readout<<<NG,256,0,stream>>>(batch, h,
      ro_w1, ro_b1, ro_w2, ro_b2, ro_w3, ro_b3, (float*)d_out);
}

// Round 8
// 3355.781 us; speedup vs baseline: 1.5168x; 1.5168x over previous
//
#include <hip/hip_runtime.h>
#include <hip/hip_bf16.h>

#define NN 50000
#define NE 1000000
#define NG 256
#define NL 6
#define NB_SCAN 196   // ceil(NN/256)
#define EB 128        // edges per block in k_edge2

__device__ __forceinline__ float siluf(float v){ return v / (1.0f + __expf(-v)); }

// ---- degree counts ----
__global__ void k_degrees(const int* __restrict__ ei, int* __restrict__ cnt_dst,
                          int* __restrict__ cnt_src){
  int e = blockIdx.x*256 + threadIdx.x;
  if (e<NE){
    atomicAdd(&cnt_dst[ei[NE+e]], 1);
    atomicAdd(&cnt_src[ei[e]], 1);
  }
}

// ---- hierarchical scan ----
__global__ void k_scan1(const int* __restrict__ cnt, int* __restrict__ roff,
                        int* __restrict__ bsum){
  __shared__ int sd[256];
  int t=threadIdx.x; int i=blockIdx.x*256+t;
  int v=(i<NN)?cnt[i]:0;
  sd[t]=v; __syncthreads();
  #pragma unroll
  for(int off=1;off<256;off<<=1){
    int xv=(t>=off)?sd[t-off]:0; __syncthreads();
    sd[t]+=xv; __syncthreads();
  }
  if(i<NN) roff[i]=sd[t]-v;
  if(t==255) bsum[blockIdx.x]=sd[t];
}
__global__ void k_scan2(const int* __restrict__ bsum, int* __restrict__ bbase,
                        int* __restrict__ roff){
  __shared__ int sd[256];
  int t=threadIdx.x;
  int v=(t<NB_SCAN)?bsum[t]:0;
  sd[t]=v; __syncthreads();
  #pragma unroll
  for(int off=1;off<256;off<<=1){
    int xv=(t>=off)?sd[t-off]:0; __syncthreads();
    sd[t]+=xv; __syncthreads();
  }
  if(t<NB_SCAN) bbase[t]=sd[t]-v;
  if(t==255) roff[NN]=sd[t];
}
__global__ void k_scan3(int* __restrict__ roff, const int* __restrict__ bbase){
  int i=blockIdx.x*256+threadIdx.x;
  if(i<NN) roff[i]+=bbase[blockIdx.x];
}

// ---- scatter-fill: dlist = edge ids in dst-sorted order; slist = dst-sorted POSITIONS per src ----
__global__ void k_fill(const int* __restrict__ ei,
                       const int* __restrict__ roff_dst, const int* __restrict__ roff_src,
                       int* __restrict__ cur_dst, int* __restrict__ cur_src,
                       int* __restrict__ dlist, int* __restrict__ slist){
  int e = blockIdx.x*256 + threadIdx.x;
  if (e<NE){
    int d = ei[NE+e];
    int pd = roff_dst[d] + atomicAdd(&cur_dst[d],1);
    dlist[pd] = e;
    int s = ei[e];
    int ps = roff_src[s] + atomicAdd(&cur_src[s],1);
    slist[ps] = pd;
  }
}

// ---- one-time gather into dst-sorted order ----
__global__ void k_gather(const int* __restrict__ ei, const float* __restrict__ ef,
                         const int* __restrict__ dlist,
                         int2* __restrict__ sd_s, float* __restrict__ ef_s){
  int p = blockIdx.x*256 + threadIdx.x;
  if (p<NE){
    int e = dlist[p];
    sd_s[p] = make_int2(ei[e], ei[NE+e]);
    const float4* src = (const float4*)(ef + (size_t)e*16);
    float4* dst = (float4*)(ef_s + (size_t)p*16);
    dst[0]=src[0]; dst[1]=src[1]; dst[2]=src[2]; dst[3]=src[3];
  }
}

// ---- init coords + 1/max(indeg,1) ----
__global__ void k_prep(const float* __restrict__ coords,
                       const int* __restrict__ cnt,
                       float* __restrict__ x, float* __restrict__ cntinv){
  int n = blockIdx.x*256+threadIdx.x;
  if (n<NN){
    x[n*3+0]=coords[n*3+0];
    x[n*3+1]=coords[n*3+1];
    x[n*3+2]=coords[n*3+2];
    cntinv[n]=1.0f/fmaxf((float)cnt[n],1.0f);
  }
}

// ==== tiled encoder ====
__global__ void __launch_bounds__(256)
k_encoder(const float* __restrict__ nf,
          const float* __restrict__ w1, const float* __restrict__ b1,
          const float* __restrict__ w2, const float* __restrict__ b2,
          float* __restrict__ h){
  __shared__ float in1[32][17];
  __shared__ float t1[32][129];
  __shared__ float wt[16][136];
  int tid=threadIdx.x;
  int g0=blockIdx.x*32;
  int ty=tid>>4, tx=tid&15;
  int n0=ty*2, n1=ty*2+1;
  { int n=tid>>3, c=(tid&7)*2;
    int gn=g0+n; if(gn>=NN) gn=NN-1;
    float2 v=*(const float2*)(nf+(size_t)gn*16+c);
    in1[n][c]=v.x; in1[n][c+1]=v.y; }
  { int c=tx*8;
    const float* src=w1+(size_t)ty*128+c;
    *(float4*)&wt[ty][c]  =*(const float4*)src;
    *(float4*)&wt[ty][c+4]=*(const float4*)(src+4); }
  __syncthreads();
  float4 a00,a01,a10,a11;
  a00=*(const float4*)(b1+tx*8); a01=*(const float4*)(b1+tx*8+4);
  a10=a00; a11=a01;
  #pragma unroll
  for(int k=0;k<16;k++){
    float m0=in1[n0][k], m1=in1[n1][k];
    float4 wa=*(float4*)&wt[k][tx*8], wb=*(float4*)&wt[k][tx*8+4];
    a00.x+=m0*wa.x; a00.y+=m0*wa.y; a00.z+=m0*wa.z; a00.w+=m0*wa.w;
    a01.x+=m0*wb.x; a01.y+=m0*wb.y; a01.z+=m0*wb.z; a01.w+=m0*wb.w;
    a10.x+=m1*wa.x; a10.y+=m1*wa.y; a10.z+=m1*wa.z; a10.w+=m1*wa.w;
    a11.x+=m1*wb.x; a11.y+=m1*wb.y; a11.z+=m1*wb.z; a11.w+=m1*wb.w;
  }
  int c8=tx*8;
  t1[n0][c8+0]=siluf(a00.x); t1[n0][c8+1]=siluf(a00.y); t1[n0][c8+2]=siluf(a00.z); t1[n0][c8+3]=siluf(a00.w);
  t1[n0][c8+4]=siluf(a01.x); t1[n0][c8+5]=siluf(a01.y); t1[n0][c8+6]=siluf(a01.z); t1[n0][c8+7]=siluf(a01.w);
  t1[n1][c8+0]=siluf(a10.x); t1[n1][c8+1]=siluf(a10.y); t1[n1][c8+2]=siluf(a10.z); t1[n1][c8+3]=siluf(a10.w);
  t1[n1][c8+4]=siluf(a11.x); t1[n1][c8+5]=siluf(a11.y); t1[n1][c8+6]=siluf(a11.z); t1[n1][c8+7]=siluf(a11.w);
  __syncthreads();
  a00=*(const float4*)(b2+c8); a01=*(const float4*)(b2+c8+4);
  a10=a00; a11=a01;
  for(int kt=0;kt<8;kt++){
    { const float* src=w2+(size_t)(kt*16+ty)*128+c8;
      *(float4*)&wt[ty][c8]  =*(const float4*)src;
      *(float4*)&wt[ty][c8+4]=*(const float4*)(src+4); }
    __syncthreads();
    #pragma unroll
    for(int kk=0;kk<16;kk++){
      int k=kt*16+kk;
      float m0=t1[n0][k], m1=t1[n1][k];
      float4 wa=*(float4*)&wt[kk][c8], wb=*(float4*)&wt[kk][c8+4];
      a00.x+=m0*wa.x; a00.y+=m0*wa.y; a00.z+=m0*wa.z; a00.w+=m0*wa.w;
      a01.x+=m0*wb.x; a01.y+=m0*wb.y; a01.z+=m0*wb.z; a01.w+=m0*wb.w;
      a10.x+=m1*wa.x; a10.y+=m1*wa.y; a10.z+=m1*wa.z; a10.w+=m1*wa.w;
      a11.x+=m1*wb.x; a11.y+=m1*wb.y; a11.z+=m1*wb.z; a11.w+=m1*wb.w;
    }
    __syncthreads();
  }
  int gn0=g0+n0, gn1=g0+n1;
  if(gn0<NN){ *(float4*)(h+(size_t)gn0*128+c8)=a00; *(float4*)(h+(size_t)gn0*128+c8+4)=a01; }
  if(gn1<NN){ *(float4*)(h+(size_t)gn1*128+c8)=a10; *(float4*)(h+(size_t)gn1*128+c8+4)=a11; }
}

// ==== standalone k_pre (layer 0 only) ====
__global__ void __launch_bounds__(256)
k_pre(const float* __restrict__ h,
      const float* __restrict__ w1, const float* __restrict__ b1,
      float* __restrict__ pa, float* __restrict__ pb){
  __shared__ float hs[32][129];
  __shared__ float wt[16][136];
  int tid=threadIdx.x;
  int g0=blockIdx.x*32;
  int ty=tid>>4, tx=tid&15;
  int n0=ty*2, n1=ty*2+1;
  { int n=tid>>3, c0=(tid&7)*16;
    int gn=g0+n; if(gn>=NN) gn=NN-1;
    const float* src=h+(size_t)gn*128+c0;
    #pragma unroll
    for(int q=0;q<4;q++){
      float4 v=*(const float4*)(src+q*4);
      hs[n][c0+q*4]=v.x; hs[n][c0+q*4+1]=v.y; hs[n][c0+q*4+2]=v.z; hs[n][c0+q*4+3]=v.w;
    } }
  int c8=tx*8;
  float4 a00,a01,a10,a11;
  if(tx<8){ a00=*(const float4*)(b1+c8); a01=*(const float4*)(b1+c8+4); }
  else    { a00=make_float4(0,0,0,0); a01=a00; }
  a10=a00; a11=a01;
  for(int kt=0;kt<8;kt++){
    { int grow=(tx<8)?(kt*16+ty):(128+kt*16+ty);
      int gcol=(tx&7)*8;
      const float* src=w1+(size_t)grow*64+gcol;
      *(float4*)&wt[ty][c8]  =*(const float4*)src;
      *(float4*)&wt[ty][c8+4]=*(const float4*)(src+4); }
    __syncthreads();
    #pragma unroll
    for(int kk=0;kk<16;kk++){
      int k=kt*16+kk;
      float m0=hs[n0][k], m1=hs[n1][k];
      float4 wa=*(float4*)&wt[kk][c8], wb=*(float4*)&wt[kk][c8+4];
      a00.x+=m0*wa.x; a00.y+=m0*wa.y; a00.z+=m0*wa.z; a00.w+=m0*wa.w;
      a01.x+=m0*wb.x; a01.y+=m0*wb.y; a01.z+=m0*wb.z; a01.w+=m0*wb.w;
      a10.x+=m1*wa.x; a10.y+=m1*wa.y; a10.z+=m1*wa.z; a10.w+=m1*wa.w;
      a11.x+=m1*wb.x; a11.y+=m1*wb.y; a11.z+=m1*wb.z; a11.w+=m1*wb.w;
    }
    __syncthreads();
  }
  int gn0=g0+n0, gn1=g0+n1;
  float* base0 = (tx<8)? (pa+(size_t)gn0*64+c8) : (pb+(size_t)gn0*64+(c8-64));
  float* base1 = (tx<8)? (pa+(size_t)gn1*64+c8) : (pb+(size_t)gn1*64+(c8-64));
  if(gn0<NN){ *(float4*)base0=a00; *(float4*)(base0+4)=a01; }
  if(gn1<NN){ *(float4*)base1=a10; *(float4*)(base1+4)=a11; }
}

// ==== fused edge kernel (round-6 GEMM loops: NO forced unroll) ====
__global__ void __launch_bounds__(256,4)
k_edge2(const int2* __restrict__ sd, const float* __restrict__ efs,
        const float* __restrict__ x,
        const float* __restrict__ pa, const float* __restrict__ pb,
        const int* __restrict__ roff_dst,
        const float* __restrict__ w1,
        const float* __restrict__ w2, const float* __restrict__ b2,
        const float* __restrict__ xw1, const float* __restrict__ xb1,
        const float* __restrict__ xw2, const float* __restrict__ xb2,
        float* __restrict__ agg, float* __restrict__ wvs){
  __shared__ float tls[EB*65];
  __shared__ float wvp[EB];
  int bid = blockIdx.x;
  int nb = (bid&7)*((int)gridDim.x>>3) + (bid>>3);
  int p0 = nb*EB;
  if (p0 >= NE) return;
  int tid = threadIdx.x;
  int wl = tid>>6, lane = tid&63;
  int eidx = (wl&1)*64 + lane;
  int c0 = __builtin_amdgcn_readfirstlane((wl>>1)*32);
  int p  = p0 + eidx;
  bool valid = (p < NE);
  float acc[32];
  float part = 0.f;
  if (valid){
    int2 sdp = sd[p];
    int s = sdp.x, d = sdp.y;
    float dx = x[s*3+0]-x[d*3+0];
    float dy = x[s*3+1]-x[d*3+1];
    float dz = x[s*3+2]-x[d*3+2];
    float sq = dx*dx+dy*dy+dz*dz;
    const float4* pa4 = (const float4*)(pa + (size_t)s*64 + c0);
    const float4* pb4 = (const float4*)(pb + (size_t)d*64 + c0);
    #pragma unroll
    for(int q=0;q<8;q++){
      float4 A=pa4[q], B=pb4[q];
      acc[q*4+0]=A.x+B.x; acc[q*4+1]=A.y+B.y; acc[q*4+2]=A.z+B.z; acc[q*4+3]=A.w+B.w;
    }
    { const float* wr = w1 + 256*64 + c0;
      #pragma unroll
      for(int j=0;j<32;j++) acc[j] += sq*wr[j]; }
    { const float4* efp=(const float4*)(efs+(size_t)p*16);
      #pragma unroll
      for(int k4=0;k4<4;k4++){
        float4 m4=efp[k4];
        float mv[4]={m4.x,m4.y,m4.z,m4.w};
        #pragma unroll
        for(int kk=0;kk<4;kk++){
          const float* wr = w1 + (257+k4*4+kk)*64 + c0;
          float m=mv[kk];
          #pragma unroll
          for(int j=0;j<32;j++) acc[j]+=m*wr[j];
        }
      } }
    #pragma unroll
    for(int j=0;j<32;j++) tls[eidx*65 + c0 + j] = siluf(acc[j]);
  }
  __syncthreads();                 // t complete
  if (valid){
    #pragma unroll
    for(int j=0;j<32;j++) acc[j]=b2[c0+j];
    for(int k=0;k<64;k++){
      float m = tls[eidx*65+k];
      const float* wr = w2 + k*64 + c0;
      #pragma unroll
      for(int j=0;j<32;j++) acc[j] += m*wr[j];
    }
    #pragma unroll
    for(int j=0;j<32;j++) acc[j]=siluf(acc[j]);   // msg half
  }
  __syncthreads();                 // all t reads done
  if (valid){
    #pragma unroll
    for(int j=0;j<32;j++) tls[eidx*65+c0+j] = acc[j];  // msg into LDS
  }
  __syncthreads();                 // msg complete
  if (valid){
    #pragma unroll
    for(int j=0;j<32;j++) acc[j]=xb1[c0+j];
    for(int k=0;k<64;k++){
      float m = tls[eidx*65+k];
      const float* wr = xw1 + k*64 + c0;
      #pragma unroll
      for(int j=0;j<32;j++) acc[j]+=m*wr[j];
    }
    const float* xw2c = xw2 + c0;
    #pragma unroll
    for(int j=0;j<32;j++) part += siluf(acc[j])*xw2c[j];
    if ((wl>>1)==0) wvp[eidx]=part;
  }
  __syncthreads();                 // wvp + msg final
  int pend = (p0+EB < NE) ? (p0+EB) : NE;
  if (valid && (wl>>1)==1) wvs[p] = wvp[eidx] + part + xb2[0];
  // fused segmented reduction over dst; exclusive segments use plain stores
  int dfirst = sd[p0].y;
  int dlast  = sd[pend-1].y;
  int j = tid&63, slot = tid>>6;
  for (int n=dfirst+slot; n<=dlast; n+=4){
    int rs0 = roff_dst[n], re0 = roff_dst[n+1];
    int rs = (rs0 > p0)   ? rs0 : p0;
    int re = (re0 < pend) ? re0 : pend;
    rs -= p0; re -= p0;
    if (re > rs){
      float sum=0.f;
      for (int r=rs; r<re; r++) sum += tls[r*65+j];
      if (rs0 >= p0 && re0 <= pend) agg[(size_t)n*64+j] = sum;      // exclusive
      else                          atomicAdd(&agg[(size_t)n*64+j], sum);
    }
  }
}

// ---- phase C: 16 lanes per src node ----
__global__ void k_coordC(const int2* __restrict__ sd,
                         const int* __restrict__ roff_src, const int* __restrict__ slist,
                         const float* __restrict__ wvs, const float* __restrict__ x,
                         float* __restrict__ cacc){
  int tid=threadIdx.x;
  int grp=tid>>4, sub=tid&15;
  int n = blockIdx.x*16 + grp;
  if (n >= NN) return;
  int s = roff_src[n], e2 = roff_src[n+1];
  float xs0=x[n*3+0], xs1=x[n*3+1], xs2=x[n*3+2];
  float a0=0.f, a1=0.f, a2=0.f;
  for (int p=s+sub; p<e2; p+=16){
    int q = slist[p];
    float w = wvs[q];
    int d = sd[q].y;
    a0 += (xs0 - x[d*3+0])*w;
    a1 += (xs1 - x[d*3+1])*w;
    a2 += (xs2 - x[d*3+2])*w;
  }
  #pragma unroll
  for(int off=1; off<16; off<<=1){
    a0 += __shfl_xor(a0, off);
    a1 += __shfl_xor(a1, off);
    a2 += __shfl_xor(a2, off);
  }
  if (sub==0){
    cacc[n*3+0]=a0; cacc[n*3+1]=a1; cacc[n*3+2]=a2;
  }
}

// ==== tiled k_node + fused next-layer pre ====
__global__ void __launch_bounds__(256)
k_node(const float* __restrict__ agg, const float* __restrict__ cacc,
       const float* __restrict__ cntinv,
       const float* __restrict__ hw1, const float* __restrict__ hb1,
       const float* __restrict__ hw2, const float* __restrict__ hb2,
       const float* __restrict__ lng, const float* __restrict__ lnb,
       float* __restrict__ h, float* __restrict__ x,
       const float* __restrict__ pw1, const float* __restrict__ pb1,
       float* __restrict__ pa, float* __restrict__ pb, int do_pre){
  __shared__ float cat[32][193];
  __shared__ float t1[32][129];
  __shared__ float wt[16][136];
  __shared__ float psA[32][8], psB[32][8];
  __shared__ float mu_s[32], rs_s[32];
  int tid=threadIdx.x;
  int g0=blockIdx.x*32;
  int ty=tid>>4, tx=tid&15;
  int n0=ty*2, n1=ty*2+1;
  int c8=tx*8;
  { int n=tid>>3, c0=(tid&7)*16;
    int gn=g0+n; if(gn>=NN) gn=NN-1;
    float ci = cntinv[gn];
    const float* src=h+(size_t)gn*128+c0;
    #pragma unroll
    for(int q=0;q<4;q++){
      float4 v=*(const float4*)(src+q*4);
      cat[n][c0+q*4]=v.x; cat[n][c0+q*4+1]=v.y; cat[n][c0+q*4+2]=v.z; cat[n][c0+q*4+3]=v.w;
    }
    int ca=(tid&7)*8;
    const float* srca=agg+(size_t)gn*64+ca;
    #pragma unroll
    for(int q=0;q<2;q++){
      float4 v=*(const float4*)(srca+q*4);
      cat[n][128+ca+q*4]=v.x*ci; cat[n][128+ca+q*4+1]=v.y*ci;
      cat[n][128+ca+q*4+2]=v.z*ci; cat[n][128+ca+q*4+3]=v.w*ci;
    } }
  float4 a00=*(const float4*)(hb1+c8), a01=*(const float4*)(hb1+c8+4);
  float4 a10=a00, a11=a01;
  for(int kt=0;kt<12;kt++){
    { const float* src=hw1+(size_t)(kt*16+ty)*128+c8;
      *(float4*)&wt[ty][c8]  =*(const float4*)src;
      *(float4*)&wt[ty][c8+4]=*(const float4*)(src+4); }
    __syncthreads();
    #pragma unroll
    for(int kk=0;kk<16;kk++){
      int k=kt*16+kk;
      float m0=cat[n0][k], m1=cat[n1][k];
      float4 wa=*(float4*)&wt[kk][c8], wb=*(float4*)&wt[kk][c8+4];
      a00.x+=m0*wa.x; a00.y+=m0*wa.y; a00.z+=m0*wa.z; a00.w+=m0*wa.w;
      a01.x+=m0*wb.x; a01.y+=m0*wb.y; a01.z+=m0*wb.z; a01.w+=m0*wb.w;
      a10.x+=m1*wa.x; a10.y+=m1*wa.y; a10.z+=m1*wa.z; a10.w+=m1*wa.w;
      a11.x+=m1*wb.x; a11.y+=m1*wb.y; a11.z+=m1*wb.z; a11.w+=m1*wb.w;
    }
    __syncthreads();
  }
  t1[n0][c8+0]=siluf(a00.x); t1[n0][c8+1]=siluf(a00.y); t1[n0][c8+2]=siluf(a00.z); t1[n0][c8+3]=siluf(a00.w);
  t1[n0][c8+4]=siluf(a01.x); t1[n0][c8+5]=siluf(a01.y); t1[n0][c8+6]=siluf(a01.z); t1[n0][c8+7]=siluf(a01.w);
  t1[n1][c8+0]=siluf(a10.x); t1[n1][c8+1]=siluf(a10.y); t1[n1][c8+2]=siluf(a10.z); t1[n1][c8+3]=siluf(a10.w);
  t1[n1][c8+4]=siluf(a11.x); t1[n1][c8+5]=siluf(a11.y); t1[n1][c8+6]=siluf(a11.z); t1[n1][c8+7]=siluf(a11.w);
  __syncthreads();
  a00=*(const float4*)(hb2+c8); a01=*(const float4*)(hb2+c8+4);
  a10=a00; a11=a01;
  for(int kt=0;kt<8;kt++){
    { const float* src=hw2+(size_t)(kt*16+ty)*128+c8;
      *(float4*)&wt[ty][c8]  =*(const float4*)src;
      *(float4*)&wt[ty][c8+4]=*(const float4*)(src+4); }
    __syncthreads();
    #pragma unroll
    for(int kk=0;kk<16;kk++){
      int k=kt*16+kk;
      float m0=t1[n0][k], m1=t1[n1][k];
      float4 wa=*(float4*)&wt[kk][c8], wb=*(float4*)&wt[kk][c8+4];
      a00.x+=m0*wa.x; a00.y+=m0*wa.y; a00.z+=m0*wa.z; a00.w+=m0*wa.w;
      a01.x+=m0*wb.x; a01.y+=m0*wb.y; a01.z+=m0*wb.z; a01.w+=m0*wb.w;
      a10.x+=m1*wa.x; a10.y+=m1*wa.y; a10.z+=m1*wa.z; a10.w+=m1*wa.w;
      a11.x+=m1*wb.x; a11.y+=m1*wb.y; a11.z+=m1*wb.z; a11.w+=m1*wb.w;
    }
    __syncthreads();
  }
  cat[n0][c8+0]+=a00.x; cat[n0][c8+1]+=a00.y; cat[n0][c8+2]+=a00.z; cat[n0][c8+3]+=a00.w;
  cat[n0][c8+4]+=a01.x; cat[n0][c8+5]+=a01.y; cat[n0][c8+6]+=a01.z; cat[n0][c8+7]+=a01.w;
  cat[n1][c8+0]+=a10.x; cat[n1][c8+1]+=a10.y; cat[n1][c8+2]+=a10.z; cat[n1][c8+3]+=a10.w;
  cat[n1][c8+4]+=a11.x; cat[n1][c8+5]+=a11.y; cat[n1][c8+6]+=a11.z; cat[n1][c8+7]+=a11.w;
  __syncthreads();
  { int rid=tid>>3, sub=tid&7;
    float sm=0.f, ss=0.f;
    #pragma unroll
    for(int i=0;i<16;i++){ float v=cat[rid][sub*16+i]; sm+=v; ss+=v*v; }
    psA[rid][sub]=sm; psB[rid][sub]=ss; }
  __syncthreads();
  { int rid=tid>>3, sub=tid&7;
    if(sub==0){
      float sm=0.f, ss=0.f;
      #pragma unroll
      for(int i=0;i<8;i++){ sm+=psA[rid][i]; ss+=psB[rid][i]; }
      float mu=sm*(1.0f/128.0f);
      float var=ss*(1.0f/128.0f)-mu*mu;
      mu_s[rid]=mu; rs_s[rid]=rsqrtf(fmaxf(var,0.0f)+1e-5f);
    } }
  __syncthreads();
  // normalize INTO cat, then store h from cat
  { int rid=tid>>3, sub=tid&7;
    int gn=g0+rid;
    float mu=mu_s[rid], rs=rs_s[rid];
    int c0=sub*16;
    #pragma unroll
    for(int q=0;q<4;q++){
      float4 g4=*(const float4*)(lng+c0+q*4);
      float4 b4=*(const float4*)(lnb+c0+q*4);
      float4 o;
      o.x=(cat[rid][c0+q*4+0]-mu)*rs*g4.x+b4.x;
      o.y=(cat[rid][c0+q*4+1]-mu)*rs*g4.y+b4.y;
      o.z=(cat[rid][c0+q*4+2]-mu)*rs*g4.z+b4.z;
      o.w=(cat[rid][c0+q*4+3]-mu)*rs*g4.w+b4.w;
      cat[rid][c0+q*4+0]=o.x; cat[rid][c0+q*4+1]=o.y;
      cat[rid][c0+q*4+2]=o.z; cat[rid][c0+q*4+3]=o.w;
      if(gn<NN) *(float4*)(h+(size_t)gn*128+c0+q*4)=o;
    } }
  if(tid<32){
    int gn=g0+tid;
    if(gn<NN){
      float ci=cntinv[gn];
      x[gn*3+0]+=cacc[gn*3+0]*ci;
      x[gn*3+1]+=cacc[gn*3+1]*ci;
      x[gn*3+2]+=cacc[gn*3+2]*ci;
    }
  }
  if(do_pre){
    __syncthreads();   // cat now holds normalized h
    float4 p00,p01,p10,p11;
    if(tx<8){ p00=*(const float4*)(pb1+c8); p01=*(const float4*)(pb1+c8+4); }
    else    { p00=make_float4(0,0,0,0); p01=p00; }
    p10=p00; p11=p01;
    for(int kt=0;kt<8;kt++){
      { int grow=(tx<8)?(kt*16+ty):(128+kt*16+ty);
        int gcol=(tx&7)*8;
        const float* src=pw1+(size_t)grow*64+gcol;
        *(float4*)&wt[ty][c8]  =*(const float4*)src;
        *(float4*)&wt[ty][c8+4]=*(const float4*)(src+4); }
      __syncthreads();
      #pragma unroll
      for(int kk=0;kk<16;kk++){
        int k=kt*16+kk;
        float m0=cat[n0][k], m1=cat[n1][k];
        float4 wa=*(float4*)&wt[kk][c8], wb=*(float4*)&wt[kk][c8+4];
        p00.x+=m0*wa.x; p00.y+=m0*wa.y; p00.z+=m0*wa.z; p00.w+=m0*wa.w;
        p01.x+=m0*wb.x; p01.y+=m0*wb.y; p01.z+=m0*wb.z; p01.w+=m0*wb.w;
        p10.x+=m1*wa.x; p10.y+=m1*wa.y; p10.z+=m1*wa.z; p10.w+=m1*wa.w;
        p11.x+=m1*wb.x; p11.y+=m1*wb.y; p11.z+=m1*wb.z; p11.w+=m1*wb.w;
      }
      __syncthreads();
    }
    int gn0=g0+n0, gn1=g0+n1;
    float* base0 = (tx<8)? (pa+(size_t)gn0*64+c8) : (pb+(size_t)gn0*64+(c8-64));
    float* base1 = (tx<8)? (pa+(size_t)gn1*64+c8) : (pb+(size_t)gn1*64+(c8-64));
    if(gn0<NN){ *(float4*)base0=p00; *(float4*)(base0+4)=p01; }
    if(gn1<NN){ *(float4*)base1=p10; *(float4*)(base1+4)=p11; }
  }
}

// ---- readout ----
__device__ __forceinline__ int lowerb(const int* a, int n, int v){
  int lo=0, hi=n;
  while(lo<hi){ int mid=(lo+hi)>>1; if(a[mid]<v) lo=mid+1; else hi=mid; }
  return lo;
}

__global__ void k_readout(const int* __restrict__ batch, const float* __restrict__ h,
                          const float* __restrict__ w1, const float* __restrict__ b1,
                          const float* __restrict__ w2, const float* __restrict__ b2,
                          const float* __restrict__ w3, const float* __restrict__ b3,
                          float* __restrict__ out){
  int g = blockIdx.x;
  int wl = threadIdx.x>>6, lane = threadIdx.x&63;
  __shared__ float part[4][128];
  __shared__ float gh[128];
  __shared__ float r1[128];
  __shared__ float r2[64];
  int start = lowerb(batch, NN, g);
  int end   = lowerb(batch, NN, g+1);
  float s0=0.f, s1=0.f;
  for(int n=start+wl; n<end; n+=4){
    s0 += h[(size_t)n*128+2*lane];
    s1 += h[(size_t)n*128+2*lane+1];
  }
  part[wl][2*lane]=s0; part[wl][2*lane+1]=s1;
  __syncthreads();
  float ci = 1.0f/fmaxf((float)(end-start),1.0f);
  if(wl==0){
    gh[2*lane]   = (part[0][2*lane]+part[1][2*lane]+part[2][2*lane]+part[3][2*lane])*ci;
    gh[2*lane+1] = (part[0][2*lane+1]+part[1][2*lane+1]+part[2][2*lane+1]+part[3][2*lane+1])*ci;
  }
  __syncthreads();
  if(wl==0){
    float a0=b1[2*lane], a1=b1[2*lane+1];
    for(int k=0;k<128;k++){
      float m=gh[k];
      float2 w=((const float2*)(w1+k*128))[lane];
      a0+=m*w.x; a1+=m*w.y;
    }
    r1[2*lane]=siluf(a0); r1[2*lane+1]=siluf(a1);
  }
  __syncthreads();
  if(wl==0){
    float b=b2[lane];
    for(int k=0;k<128;k++) b += r1[k]*w2[k*64+lane];
    r2[lane]=siluf(b);
  }
  __syncthreads();
  if(wl==0 && lane<2){
    float o=b3[lane];
    for(int k=0;k<64;k++) o += r2[k]*w3[k*2+lane];
    out[g*2+lane]=o;
  }
}

extern "C" void kernel_launch(void* const* d_in, const int* in_sizes, int n_in,
                              void* d_out, int out_size, void* d_ws, size_t ws_size,
                              hipStream_t stream){
  const float* nf     = (const float*)d_in[0];
  const float* coords = (const float*)d_in[1];
  const int*   ei     = (const int*)d_in[2];
  const float* ef     = (const float*)d_in[3];
  const int*   batch  = (const int*)d_in[4];

  const float* enc_w1 = (const float*)d_in[5];
  const float* enc_b1 = (const float*)d_in[6];
  const float* enc_w2 = (const float*)d_in[7];
  const float* enc_b2 = (const float*)d_in[8];
  const float* pe_w1  = (const float*)d_in[9];
  const float* pe_b1  = (const float*)d_in[10];
  const float* pe_w2  = (const float*)d_in[11];
  const float* pe_b2  = (const float*)d_in[12];
  const float* ph_w1  = (const float*)d_in[13];
  const float* ph_b1  = (const float*)d_in[14];
  const float* ph_w2  = (const float*)d_in[15];
  const float* ph_b2  = (const float*)d_in[16];
  const float* px_w1  = (const float*)d_in[17];
  const float* px_b1  = (const float*)d_in[18];
  const float* px_w2  = (const float*)d_in[19];
  const float* px_b2  = (const float*)d_in[20];
  const float* ln_g   = (const float*)d_in[21];
  const float* ln_b   = (const float*)d_in[22];
  const float* ro_w1  = (const float*)d_in[23];
  const float* ro_b1  = (const float*)d_in[24];
  const float* ro_w2  = (const float*)d_in[25];
  const float* ro_b2  = (const float*)d_in[26];
  const float* ro_w3  = (const float*)d_in[27];
  const float* ro_b3  = (const float*)d_in[28];

  char* wsb = (char*)d_ws;
  size_t off = 0;
  auto alloc_f = [&](size_t nfl)->float*{ float* p=(float*)(wsb+off); off+=nfl*4; return p; };
  auto alloc_i = [&](size_t nin)->int*  { int*   p=(int*)(wsb+off);   off+=nin*4; return p; };

  float* h      = alloc_f((size_t)NN*128);
  float* x      = alloc_f((size_t)NN*3);
  float* agg    = alloc_f((size_t)NN*64);
  float* cacc   = alloc_f((size_t)NN*3);
  float* cntinv = alloc_f(NN);
  float* pa     = alloc_f((size_t)NN*64);
  float* pb     = alloc_f((size_t)NN*64);
  float* wvs    = alloc_f(NE);
  float* ef_s   = alloc_f((size_t)NE*16);
  int2*  sd_s   = (int2*)alloc_i((size_t)NE*2);
  int* roff_dst = alloc_i(NN+1);
  int* roff_src = alloc_i(NN+1);
  int* dlist    = alloc_i(NE);
  int* slist    = alloc_i(NE);
  int* bsum     = alloc_i(256);
  int* bbase    = alloc_i(256);
  int* cnt_dst  = alloc_i(NN);   // cnt_dst..cur_src contiguous -> one memset
  int* cnt_src  = alloc_i(NN);
  int* cur_dst  = alloc_i(NN);
  int* cur_src  = alloc_i(NN);

  hipMemsetAsync(cnt_dst, 0, (size_t)4*NN*sizeof(int), stream);
  k_degrees<<<(NE+255)/256,256,0,stream>>>(ei, cnt_dst, cnt_src);
  k_scan1<<<NB_SCAN,256,0,stream>>>(cnt_dst, roff_dst, bsum);
  k_scan2<<<1,256,0,stream>>>(bsum, bbase, roff_dst);
  k_scan3<<<NB_SCAN,256,0,stream>>>(roff_dst, bbase);
  k_scan1<<<NB_SCAN,256,0,stream>>>(cnt_src, roff_src, bsum);
  k_scan2<<<1,256,0,stream>>>(bsum, bbase, roff_src);
  k_scan3<<<NB_SCAN,256,0,stream>>>(roff_src, bbase);
  k_fill<<<(NE+255)/256,256,0,stream>>>(ei, roff_dst, roff_src, cur_dst, cur_src, dlist, slist);
  k_gather<<<(NE+255)/256,256,0,stream>>>(ei, ef, dlist, sd_s, ef_s);
  k_prep<<<(NN+255)/256,256,0,stream>>>(coords, cnt_dst, x, cntinv);
  k_encoder<<<(NN+31)/32,256,0,stream>>>(nf, enc_w1, enc_b1, enc_w2, enc_b2, h);
  k_pre<<<(NN+31)/32,256,0,stream>>>(h, pe_w1, pe_b1, pa, pb);   // layer 0

  int G  = (NE+EB-1)/EB;
  int G8 = ((G+7)/8)*8;

  for(int l=0;l<NL;l++){
    hipMemsetAsync(agg, 0, (size_t)NN*64*sizeof(float), stream);
    k_edge2<<<G8,256,0,stream>>>(sd_s, ef_s, x, pa, pb, roff_dst,
        pe_w1+(size_t)l*273*64,
        pe_w2+(size_t)l*64*64, pe_b2+l*64,
        px_w1+(size_t)l*64*64, px_b1+l*64,
        px_w2+l*64, px_b2+l,
        agg, wvs);
    k_coordC<<<(NN+15)/16,256,0,stream>>>(sd_s, roff_src, slist, wvs, x, cacc);
    int nl2 = l+1;
    int do_pre = (nl2 < NL) ? 1 : 0;
    const float* pw1n = pe_w1 + (size_t)(do_pre? nl2:0)*273*64;
    const float* pb1n = pe_b1 + (size_t)(do_pre? nl2:0)*64;
    k_node<<<(NN+31)/32,256,0,stream>>>(agg, cacc, cntinv,
        ph_w1+(size_t)l*192*128, ph_b1+l*128,
        ph_w2+(size_t)l*128*128, ph_b2+l*128,
        ln_g+l*128, ln_b+l*128, h, x,
        pw1n, pb1n, pa, pb, do_pre);
  }

  k_readout<<<NG,256,0,stream>>>(batch, h,
      ro_w1, ro_b1, ro_w2, ro_b2, ro_w3, ro_b3, (float*)d_out);
}

// Round 9
// 3310.769 us; speedup vs baseline: 1.5374x; 1.0136x over previous
//
#include <hip/hip_runtime.h>
#include <hip/hip_bf16.h>

#define NN 50000
#define NE 1000000
#define NG 256
#define NL 6
#define NB_SCAN 196   // ceil(NN/256)
#define EB 128        // edges per block in k_edge2

typedef float v2f __attribute__((ext_vector_type(2)));

__device__ __forceinline__ float siluf(float v){ return v / (1.0f + __expf(-v)); }

// ---- degree counts ----
__global__ void k_degrees(const int* __restrict__ ei, int* __restrict__ cnt_dst,
                          int* __restrict__ cnt_src){
  int e = blockIdx.x*256 + threadIdx.x;
  if (e<NE){
    atomicAdd(&cnt_dst[ei[NE+e]], 1);
    atomicAdd(&cnt_src[ei[e]], 1);
  }
}

// ---- hierarchical scan ----
__global__ void k_scan1(const int* __restrict__ cnt, int* __restrict__ roff,
                        int* __restrict__ bsum){
  __shared__ int sd[256];
  int t=threadIdx.x; int i=blockIdx.x*256+t;
  int v=(i<NN)?cnt[i]:0;
  sd[t]=v; __syncthreads();
  #pragma unroll
  for(int off=1;off<256;off<<=1){
    int xv=(t>=off)?sd[t-off]:0; __syncthreads();
    sd[t]+=xv; __syncthreads();
  }
  if(i<NN) roff[i]=sd[t]-v;
  if(t==255) bsum[blockIdx.x]=sd[t];
}
__global__ void k_scan2(const int* __restrict__ bsum, int* __restrict__ bbase,
                        int* __restrict__ roff){
  __shared__ int sd[256];
  int t=threadIdx.x;
  int v=(t<NB_SCAN)?bsum[t]:0;
  sd[t]=v; __syncthreads();
  #pragma unroll
  for(int off=1;off<256;off<<=1){
    int xv=(t>=off)?sd[t-off]:0; __syncthreads();
    sd[t]+=xv; __syncthreads();
  }
  if(t<NB_SCAN) bbase[t]=sd[t]-v;
  if(t==255) roff[NN]=sd[t];
}
__global__ void k_scan3(int* __restrict__ roff, const int* __restrict__ bbase){
  int i=blockIdx.x*256+threadIdx.x;
  if(i<NN) roff[i]+=bbase[blockIdx.x];
}

// ---- scatter-fill: dlist = edge ids dst-sorted; slist = dst-sorted POSITIONS per src ----
__global__ void k_fill(const int* __restrict__ ei,
                       const int* __restrict__ roff_dst, const int* __restrict__ roff_src,
                       int* __restrict__ cur_dst, int* __restrict__ cur_src,
                       int* __restrict__ dlist, int* __restrict__ slist){
  int e = blockIdx.x*256 + threadIdx.x;
  if (e<NE){
    int d = ei[NE+e];
    int pd = roff_dst[d] + atomicAdd(&cur_dst[d],1);
    dlist[pd] = e;
    int s = ei[e];
    int ps = roff_src[s] + atomicAdd(&cur_src[s],1);
    slist[ps] = pd;
  }
}

// ---- one-time gather into dst-sorted order ----
__global__ void k_gather(const int* __restrict__ ei, const float* __restrict__ ef,
                         const int* __restrict__ dlist,
                         int2* __restrict__ sd_s, float* __restrict__ ef_s){
  int p = blockIdx.x*256 + threadIdx.x;
  if (p<NE){
    int e = dlist[p];
    sd_s[p] = make_int2(ei[e], ei[NE+e]);
    const float4* src = (const float4*)(ef + (size_t)e*16);
    float4* dst = (float4*)(ef_s + (size_t)p*16);
    dst[0]=src[0]; dst[1]=src[1]; dst[2]=src[2]; dst[3]=src[3];
  }
}

// ---- init coords + 1/max(indeg,1) ----
__global__ void k_prep(const float* __restrict__ coords,
                       const int* __restrict__ cnt,
                       float* __restrict__ x, float* __restrict__ cntinv){
  int n = blockIdx.x*256+threadIdx.x;
  if (n<NN){
    x[n*3+0]=coords[n*3+0];
    x[n*3+1]=coords[n*3+1];
    x[n*3+2]=coords[n*3+2];
    cntinv[n]=1.0f/fmaxf((float)cnt[n],1.0f);
  }
}

// ==== tiled encoder ====
__global__ void __launch_bounds__(256)
k_encoder(const float* __restrict__ nf,
          const float* __restrict__ w1, const float* __restrict__ b1,
          const float* __restrict__ w2, const float* __restrict__ b2,
          float* __restrict__ h){
  __shared__ float in1[32][17];
  __shared__ float t1[32][129];
  __shared__ float wt[16][136];
  int tid=threadIdx.x;
  int g0=blockIdx.x*32;
  int ty=tid>>4, tx=tid&15;
  int n0=ty*2, n1=ty*2+1;
  { int n=tid>>3, c=(tid&7)*2;
    int gn=g0+n; if(gn>=NN) gn=NN-1;
    float2 v=*(const float2*)(nf+(size_t)gn*16+c);
    in1[n][c]=v.x; in1[n][c+1]=v.y; }
  { int c=tx*8;
    const float* src=w1+(size_t)ty*128+c;
    *(float4*)&wt[ty][c]  =*(const float4*)src;
    *(float4*)&wt[ty][c+4]=*(const float4*)(src+4); }
  __syncthreads();
  float4 a00,a01,a10,a11;
  a00=*(const float4*)(b1+tx*8); a01=*(const float4*)(b1+tx*8+4);
  a10=a00; a11=a01;
  #pragma unroll
  for(int k=0;k<16;k++){
    float m0=in1[n0][k], m1=in1[n1][k];
    float4 wa=*(float4*)&wt[k][tx*8], wb=*(float4*)&wt[k][tx*8+4];
    a00.x+=m0*wa.x; a00.y+=m0*wa.y; a00.z+=m0*wa.z; a00.w+=m0*wa.w;
    a01.x+=m0*wb.x; a01.y+=m0*wb.y; a01.z+=m0*wb.z; a01.w+=m0*wb.w;
    a10.x+=m1*wa.x; a10.y+=m1*wa.y; a10.z+=m1*wa.z; a10.w+=m1*wa.w;
    a11.x+=m1*wb.x; a11.y+=m1*wb.y; a11.z+=m1*wb.z; a11.w+=m1*wb.w;
  }
  int c8=tx*8;
  t1[n0][c8+0]=siluf(a00.x); t1[n0][c8+1]=siluf(a00.y); t1[n0][c8+2]=siluf(a00.z); t1[n0][c8+3]=siluf(a00.w);
  t1[n0][c8+4]=siluf(a01.x); t1[n0][c8+5]=siluf(a01.y); t1[n0][c8+6]=siluf(a01.z); t1[n0][c8+7]=siluf(a01.w);
  t1[n1][c8+0]=siluf(a10.x); t1[n1][c8+1]=siluf(a10.y); t1[n1][c8+2]=siluf(a10.z); t1[n1][c8+3]=siluf(a10.w);
  t1[n1][c8+4]=siluf(a11.x); t1[n1][c8+5]=siluf(a11.y); t1[n1][c8+6]=siluf(a11.z); t1[n1][c8+7]=siluf(a11.w);
  __syncthreads();
  a00=*(const float4*)(b2+c8); a01=*(const float4*)(b2+c8+4);
  a10=a00; a11=a01;
  for(int kt=0;kt<8;kt++){
    { const float* src=w2+(size_t)(kt*16+ty)*128+c8;
      *(float4*)&wt[ty][c8]  =*(const float4*)src;
      *(float4*)&wt[ty][c8+4]=*(const float4*)(src+4); }
    __syncthreads();
    #pragma unroll
    for(int kk=0;kk<16;kk++){
      int k=kt*16+kk;
      float m0=t1[n0][k], m1=t1[n1][k];
      float4 wa=*(float4*)&wt[kk][c8], wb=*(float4*)&wt[kk][c8+4];
      a00.x+=m0*wa.x; a00.y+=m0*wa.y; a00.z+=m0*wa.z; a00.w+=m0*wa.w;
      a01.x+=m0*wb.x; a01.y+=m0*wb.y; a01.z+=m0*wb.z; a01.w+=m0*wb.w;
      a10.x+=m1*wa.x; a10.y+=m1*wa.y; a10.z+=m1*wa.z; a10.w+=m1*wa.w;
      a11.x+=m1*wb.x; a11.y+=m1*wb.y; a11.z+=m1*wb.z; a11.w+=m1*wb.w;
    }
    __syncthreads();
  }
  int gn0=g0+n0, gn1=g0+n1;
  if(gn0<NN){ *(float4*)(h+(size_t)gn0*128+c8)=a00; *(float4*)(h+(size_t)gn0*128+c8+4)=a01; }
  if(gn1<NN){ *(float4*)(h+(size_t)gn1*128+c8)=a10; *(float4*)(h+(size_t)gn1*128+c8+4)=a11; }
}

// ==== tiled k_pre (every layer) ====
__global__ void __launch_bounds__(256)
k_pre(const float* __restrict__ h,
      const float* __restrict__ w1, const float* __restrict__ b1,
      float* __restrict__ pa, float* __restrict__ pb){
  __shared__ float hs[32][129];
  __shared__ float wt[16][136];
  int tid=threadIdx.x;
  int g0=blockIdx.x*32;
  int ty=tid>>4, tx=tid&15;
  int n0=ty*2, n1=ty*2+1;
  { int n=tid>>3, c0=(tid&7)*16;
    int gn=g0+n; if(gn>=NN) gn=NN-1;
    const float* src=h+(size_t)gn*128+c0;
    #pragma unroll
    for(int q=0;q<4;q++){
      float4 v=*(const float4*)(src+q*4);
      hs[n][c0+q*4]=v.x; hs[n][c0+q*4+1]=v.y; hs[n][c0+q*4+2]=v.z; hs[n][c0+q*4+3]=v.w;
    } }
  int c8=tx*8;
  float4 a00,a01,a10,a11;
  if(tx<8){ a00=*(const float4*)(b1+c8); a01=*(const float4*)(b1+c8+4); }
  else    { a00=make_float4(0,0,0,0); a01=a00; }
  a10=a00; a11=a01;
  for(int kt=0;kt<8;kt++){
    { int grow=(tx<8)?(kt*16+ty):(128+kt*16+ty);
      int gcol=(tx&7)*8;
      const float* src=w1+(size_t)grow*64+gcol;
      *(float4*)&wt[ty][c8]  =*(const float4*)src;
      *(float4*)&wt[ty][c8+4]=*(const float4*)(src+4); }
    __syncthreads();
    #pragma unroll
    for(int kk=0;kk<16;kk++){
      int k=kt*16+kk;
      float m0=hs[n0][k], m1=hs[n1][k];
      float4 wa=*(float4*)&wt[kk][c8], wb=*(float4*)&wt[kk][c8+4];
      a00.x+=m0*wa.x; a00.y+=m0*wa.y; a00.z+=m0*wa.z; a00.w+=m0*wa.w;
      a01.x+=m0*wb.x; a01.y+=m0*wb.y; a01.z+=m0*wb.z; a01.w+=m0*wb.w;
      a10.x+=m1*wa.x; a10.y+=m1*wa.y; a10.z+=m1*wa.z; a10.w+=m1*wa.w;
      a11.x+=m1*wb.x; a11.y+=m1*wb.y; a11.z+=m1*wb.z; a11.w+=m1*wb.w;
    }
    __syncthreads();
  }
  int gn0=g0+n0, gn1=g0+n1;
  float* base0 = (tx<8)? (pa+(size_t)gn0*64+c8) : (pb+(size_t)gn0*64+(c8-64));
  float* base1 = (tx<8)? (pa+(size_t)gn1*64+c8) : (pb+(size_t)gn1*64+(c8-64));
  if(gn0<NN){ *(float4*)base0=a00; *(float4*)(base0+4)=a01; }
  if(gn1<NN){ *(float4*)base1=a10; *(float4*)(base1+4)=a11; }
}

// ==== fused edge kernel — packed fp32 (v2f) GEMM loops ====
__global__ void __launch_bounds__(256,4)
k_edge2(const int2* __restrict__ sd, const float* __restrict__ efs,
        const float* __restrict__ x,
        const float* __restrict__ pa, const float* __restrict__ pb,
        const int* __restrict__ roff_dst,
        const float* __restrict__ w1,
        const float* __restrict__ w2, const float* __restrict__ b2,
        const float* __restrict__ xw1, const float* __restrict__ xb1,
        const float* __restrict__ xw2, const float* __restrict__ xb2,
        float* __restrict__ agg, float* __restrict__ wvs){
  __shared__ float tls[EB*65];
  __shared__ float wvp[EB];
  int bid = blockIdx.x;
  int nb = (bid&7)*((int)gridDim.x>>3) + (bid>>3);
  int p0 = nb*EB;
  if (p0 >= NE) return;
  int tid = threadIdx.x;
  int wl = tid>>6, lane = tid&63;
  int eidx = (wl&1)*64 + lane;
  int c0 = __builtin_amdgcn_readfirstlane((wl>>1)*32);
  int p  = p0 + eidx;
  bool valid = (p < NE);
  v2f acc[16];
  float part = 0.f;
  if (valid){
    int2 sdp = sd[p];
    int s = sdp.x, d = sdp.y;
    float dx = x[s*3+0]-x[d*3+0];
    float dy = x[s*3+1]-x[d*3+1];
    float dz = x[s*3+2]-x[d*3+2];
    float sq = dx*dx+dy*dy+dz*dz;
    const float4* pa4 = (const float4*)(pa + (size_t)s*64 + c0);
    const float4* pb4 = (const float4*)(pb + (size_t)d*64 + c0);
    #pragma unroll
    for(int q=0;q<8;q++){
      float4 A=pa4[q], B=pb4[q];
      v2f lo = {A.x+B.x, A.y+B.y};
      v2f hi = {A.z+B.z, A.w+B.w};
      acc[q*2+0]=lo; acc[q*2+1]=hi;
    }
    { const v2f* wr = (const v2f*)(w1 + 256*64 + c0);
      v2f sq2 = {sq, sq};
      #pragma unroll
      for(int j=0;j<16;j++) acc[j] += sq2*wr[j]; }
    { const float4* efp=(const float4*)(efs+(size_t)p*16);
      #pragma unroll
      for(int k4=0;k4<4;k4++){
        float4 m4=efp[k4];
        float mv[4]={m4.x,m4.y,m4.z,m4.w};
        #pragma unroll
        for(int kk=0;kk<4;kk++){
          const v2f* wr = (const v2f*)(w1 + (257+k4*4+kk)*64 + c0);
          v2f m2 = {mv[kk], mv[kk]};
          #pragma unroll
          for(int j=0;j<16;j++) acc[j]+=m2*wr[j];
        }
      } }
    #pragma unroll
    for(int j=0;j<16;j++){
      tls[eidx*65+c0+2*j]   = siluf(acc[j].x);
      tls[eidx*65+c0+2*j+1] = siluf(acc[j].y);
    }
  }
  __syncthreads();                 // t complete
  if (valid){
    { const v2f* b2v=(const v2f*)(b2+c0);
      #pragma unroll
      for(int j=0;j<16;j++) acc[j]=b2v[j]; }
    for(int k=0;k<64;k++){
      float m = tls[eidx*65+k];
      const v2f* wr = (const v2f*)(w2 + k*64 + c0);
      v2f m2 = {m, m};
      #pragma unroll
      for(int j=0;j<16;j++) acc[j] += m2*wr[j];
    }
    #pragma unroll
    for(int j=0;j<16;j++){ acc[j].x=siluf(acc[j].x); acc[j].y=siluf(acc[j].y); }
  }
  __syncthreads();                 // all t reads done
  if (valid){
    #pragma unroll
    for(int j=0;j<16;j++){
      tls[eidx*65+c0+2*j]   = acc[j].x;
      tls[eidx*65+c0+2*j+1] = acc[j].y;
    }
  }
  __syncthreads();                 // msg complete
  if (valid){
    { const v2f* xbv=(const v2f*)(xb1+c0);
      #pragma unroll
      for(int j=0;j<16;j++) acc[j]=xbv[j]; }
    for(int k=0;k<64;k++){
      float m = tls[eidx*65+k];
      const v2f* wr = (const v2f*)(xw1 + k*64 + c0);
      v2f m2 = {m, m};
      #pragma unroll
      for(int j=0;j<16;j++) acc[j]+=m2*wr[j];
    }
    const float* xw2c = xw2 + c0;
    #pragma unroll
    for(int j=0;j<16;j++) part += siluf(acc[j].x)*xw2c[2*j] + siluf(acc[j].y)*xw2c[2*j+1];
    if ((wl>>1)==0) wvp[eidx]=part;
  }
  __syncthreads();                 // wvp + msg final
  int pend = (p0+EB < NE) ? (p0+EB) : NE;
  if (valid && (wl>>1)==1) wvs[p] = wvp[eidx] + part + xb2[0];
  // fused segmented reduction over dst; exclusive segments use plain stores
  int dfirst = sd[p0].y;
  int dlast  = sd[pend-1].y;
  int j = tid&63, slot = tid>>6;
  for (int n=dfirst+slot; n<=dlast; n+=4){
    int rs0 = roff_dst[n], re0 = roff_dst[n+1];
    int rs = (rs0 > p0)   ? rs0 : p0;
    int re = (re0 < pend) ? re0 : pend;
    rs -= p0; re -= p0;
    if (re > rs){
      float sum=0.f;
      for (int r=rs; r<re; r++) sum += tls[r*65+j];
      if (rs0 >= p0 && re0 <= pend) agg[(size_t)n*64+j] = sum;      // exclusive
      else                          atomicAdd(&agg[(size_t)n*64+j], sum);
    }
  }
}

// ---- phase C: 16 lanes per src node ----
__global__ void k_coordC(const int2* __restrict__ sd,
                         const int* __restrict__ roff_src, const int* __restrict__ slist,
                         const float* __restrict__ wvs, const float* __restrict__ x,
                         float* __restrict__ cacc){
  int tid=threadIdx.x;
  int grp=tid>>4, sub=tid&15;
  int n = blockIdx.x*16 + grp;
  if (n >= NN) return;
  int s = roff_src[n], e2 = roff_src[n+1];
  float xs0=x[n*3+0], xs1=x[n*3+1], xs2=x[n*3+2];
  float a0=0.f, a1=0.f, a2=0.f;
  for (int p=s+sub; p<e2; p+=16){
    int q = slist[p];
    float w = wvs[q];
    int d = sd[q].y;
    a0 += (xs0 - x[d*3+0])*w;
    a1 += (xs1 - x[d*3+1])*w;
    a2 += (xs2 - x[d*3+2])*w;
  }
  #pragma unroll
  for(int off=1; off<16; off<<=1){
    a0 += __shfl_xor(a0, off);
    a1 += __shfl_xor(a1, off);
    a2 += __shfl_xor(a2, off);
  }
  if (sub==0){
    cacc[n*3+0]=a0; cacc[n*3+1]=a1; cacc[n*3+2]=a2;
  }
}

// ==== tiled k_node (round-6 version: no fused pre) ====
__global__ void __launch_bounds__(256)
k_node(const float* __restrict__ agg, const float* __restrict__ cacc,
       const float* __restrict__ cntinv,
       const float* __restrict__ hw1, const float* __restrict__ hb1,
       const float* __restrict__ hw2, const float* __restrict__ hb2,
       const float* __restrict__ lng, const float* __restrict__ lnb,
       float* __restrict__ h, float* __restrict__ x){
  __shared__ float cat[32][193];
  __shared__ float t1[32][129];
  __shared__ float wt[16][136];
  __shared__ float psA[32][8], psB[32][8];
  __shared__ float mu_s[32], rs_s[32];
  int tid=threadIdx.x;
  int g0=blockIdx.x*32;
  int ty=tid>>4, tx=tid&15;
  int n0=ty*2, n1=ty*2+1;
  int c8=tx*8;
  { int n=tid>>3, c0=(tid&7)*16;
    int gn=g0+n; if(gn>=NN) gn=NN-1;
    float ci = cntinv[gn];
    const float* src=h+(size_t)gn*128+c0;
    #pragma unroll
    for(int q=0;q<4;q++){
      float4 v=*(const float4*)(src+q*4);
      cat[n][c0+q*4]=v.x; cat[n][c0+q*4+1]=v.y; cat[n][c0+q*4+2]=v.z; cat[n][c0+q*4+3]=v.w;
    }
    int ca=(tid&7)*8;
    const float* srca=agg+(size_t)gn*64+ca;
    #pragma unroll
    for(int q=0;q<2;q++){
      float4 v=*(const float4*)(srca+q*4);
      cat[n][128+ca+q*4]=v.x*ci; cat[n][128+ca+q*4+1]=v.y*ci;
      cat[n][128+ca+q*4+2]=v.z*ci; cat[n][128+ca+q*4+3]=v.w*ci;
    } }
  float4 a00=*(const float4*)(hb1+c8), a01=*(const float4*)(hb1+c8+4);
  float4 a10=a00, a11=a01;
  for(int kt=0;kt<12;kt++){
    { const float* src=hw1+(size_t)(kt*16+ty)*128+c8;
      *(float4*)&wt[ty][c8]  =*(const float4*)src;
      *(float4*)&wt[ty][c8+4]=*(const float4*)(src+4); }
    __syncthreads();
    #pragma unroll
    for(int kk=0;kk<16;kk++){
      int k=kt*16+kk;
      float m0=cat[n0][k], m1=cat[n1][k];
      float4 wa=*(float4*)&wt[kk][c8], wb=*(float4*)&wt[kk][c8+4];
      a00.x+=m0*wa.x; a00.y+=m0*wa.y; a00.z+=m0*wa.z; a00.w+=m0*wa.w;
      a01.x+=m0*wb.x; a01.y+=m0*wb.y; a01.z+=m0*wb.z; a01.w+=m0*wb.w;
      a10.x+=m1*wa.x; a10.y+=m1*wa.y; a10.z+=m1*wa.z; a10.w+=m1*wa.w;
      a11.x+=m1*wb.x; a11.y+=m1*wb.y; a11.z+=m1*wb.z; a11.w+=m1*wb.w;
    }
    __syncthreads();
  }
  t1[n0][c8+0]=siluf(a00.x); t1[n0][c8+1]=siluf(a00.y); t1[n0][c8+2]=siluf(a00.z); t1[n0][c8+3]=siluf(a00.w);
  t1[n0][c8+4]=siluf(a01.x); t1[n0][c8+5]=siluf(a01.y); t1[n0][c8+6]=siluf(a01.z); t1[n0][c8+7]=siluf(a01.w);
  t1[n1][c8+0]=siluf(a10.x); t1[n1][c8+1]=siluf(a10.y); t1[n1][c8+2]=siluf(a10.z); t1[n1][c8+3]=siluf(a10.w);
  t1[n1][c8+4]=siluf(a11.x); t1[n1][c8+5]=siluf(a11.y); t1[n1][c8+6]=siluf(a11.z); t1[n1][c8+7]=siluf(a11.w);
  __syncthreads();
  a00=*(const float4*)(hb2+c8); a01=*(const float4*)(hb2+c8+4);
  a10=a00; a11=a01;
  for(int kt=0;kt<8;kt++){
    { const float* src=hw2+(size_t)(kt*16+ty)*128+c8;
      *(float4*)&wt[ty][c8]  =*(const float4*)src;
      *(float4*)&wt[ty][c8+4]=*(const float4*)(src+4); }
    __syncthreads();
    #pragma unroll
    for(int kk=0;kk<16;kk++){
      int k=kt*16+kk;
      float m0=t1[n0][k], m1=t1[n1][k];
      float4 wa=*(float4*)&wt[kk][c8], wb=*(float4*)&wt[kk][c8+4];
      a00.x+=m0*wa.x; a00.y+=m0*wa.y; a00.z+=m0*wa.z; a00.w+=m0*wa.w;
      a01.x+=m0*wb.x; a01.y+=m0*wb.y; a01.z+=m0*wb.z; a01.w+=m0*wb.w;
      a10.x+=m1*wa.x; a10.y+=m1*wa.y; a10.z+=m1*wa.z; a10.w+=m1*wa.w;
      a11.x+=m1*wb.x; a11.y+=m1*wb.y; a11.z+=m1*wb.z; a11.w+=m1*wb.w;
    }
    __syncthreads();
  }
  cat[n0][c8+0]+=a00.x; cat[n0][c8+1]+=a00.y; cat[n0][c8+2]+=a00.z; cat[n0][c8+3]+=a00.w;
  cat[n0][c8+4]+=a01.x; cat[n0][c8+5]+=a01.y; cat[n0][c8+6]+=a01.z; cat[n0][c8+7]+=a01.w;
  cat[n1][c8+0]+=a10.x; cat[n1][c8+1]+=a10.y; cat[n1][c8+2]+=a10.z; cat[n1][c8+3]+=a10.w;
  cat[n1][c8+4]+=a11.x; cat[n1][c8+5]+=a11.y; cat[n1][c8+6]+=a11.z; cat[n1][c8+7]+=a11.w;
  __syncthreads();
  { int rid=tid>>3, sub=tid&7;
    float sm=0.f, ss=0.f;
    #pragma unroll
    for(int i=0;i<16;i++){ float v=cat[rid][sub*16+i]; sm+=v; ss+=v*v; }
    psA[rid][sub]=sm; psB[rid][sub]=ss; }
  __syncthreads();
  { int rid=tid>>3, sub=tid&7;
    if(sub==0){
      float sm=0.f, ss=0.f;
      #pragma unroll
      for(int i=0;i<8;i++){ sm+=psA[rid][i]; ss+=psB[rid][i]; }
      float mu=sm*(1.0f/128.0f);
      float var=ss*(1.0f/128.0f)-mu*mu;
      mu_s[rid]=mu; rs_s[rid]=rsqrtf(fmaxf(var,0.0f)+1e-5f);
    } }
  __syncthreads();
  { int rid=tid>>3, sub=tid&7;
    int gn=g0+rid;
    if(gn<NN){
      float mu=mu_s[rid], rs=rs_s[rid];
      int c0=sub*16;
      #pragma unroll
      for(int q=0;q<4;q++){
        float4 g4=*(const float4*)(lng+c0+q*4);
        float4 b4=*(const float4*)(lnb+c0+q*4);
        float4 o;
        o.x=(cat[rid][c0+q*4+0]-mu)*rs*g4.x+b4.x;
        o.y=(cat[rid][c0+q*4+1]-mu)*rs*g4.y+b4.y;
        o.z=(cat[rid][c0+q*4+2]-mu)*rs*g4.z+b4.z;
        o.w=(cat[rid][c0+q*4+3]-mu)*rs*g4.w+b4.w;
        *(float4*)(h+(size_t)gn*128+c0+q*4)=o;
      }
    } }
  if(tid<32){
    int gn=g0+tid;
    if(gn<NN){
      float ci=cntinv[gn];
      x[gn*3+0]+=cacc[gn*3+0]*ci;
      x[gn*3+1]+=cacc[gn*3+1]*ci;
      x[gn*3+2]+=cacc[gn*3+2]*ci;
    }
  }
}

// ---- readout ----
__device__ __forceinline__ int lowerb(const int* a, int n, int v){
  int lo=0, hi=n;
  while(lo<hi){ int mid=(lo+hi)>>1; if(a[mid]<v) lo=mid+1; else hi=mid; }
  return lo;
}

__global__ void k_readout(const int* __restrict__ batch, const float* __restrict__ h,
                          const float* __restrict__ w1, const float* __restrict__ b1,
                          const float* __restrict__ w2, const float* __restrict__ b2,
                          const float* __restrict__ w3, const float* __restrict__ b3,
                          float* __restrict__ out){
  int g = blockIdx.x;
  int wl = threadIdx.x>>6, lane = threadIdx.x&63;
  __shared__ float part[4][128];
  __shared__ float gh[128];
  __shared__ float r1[128];
  __shared__ float r2[64];
  int start = lowerb(batch, NN, g);
  int end   = lowerb(batch, NN, g+1);
  float s0=0.f, s1=0.f;
  for(int n=start+wl; n<end; n+=4){
    s0 += h[(size_t)n*128+2*lane];
    s1 += h[(size_t)n*128+2*lane+1];
  }
  part[wl][2*lane]=s0; part[wl][2*lane+1]=s1;
  __syncthreads();
  float ci = 1.0f/fmaxf((float)(end-start),1.0f);
  if(wl==0){
    gh[2*lane]   = (part[0][2*lane]+part[1][2*lane]+part[2][2*lane]+part[3][2*lane])*ci;
    gh[2*lane+1] = (part[0][2*lane+1]+part[1][2*lane+1]+part[2][2*lane+1]+part[3][2*lane+1])*ci;
  }
  __syncthreads();
  if(wl==0){
    float a0=b1[2*lane], a1=b1[2*lane+1];
    for(int k=0;k<128;k++){
      float m=gh[k];
      float2 w=((const float2*)(w1+k*128))[lane];
      a0+=m*w.x; a1+=m*w.y;
    }
    r1[2*lane]=siluf(a0); r1[2*lane+1]=siluf(a1);
  }
  __syncthreads();
  if(wl==0){
    float b=b2[lane];
    for(int k=0;k<128;k++) b += r1[k]*w2[k*64+lane];
    r2[lane]=siluf(b);
  }
  __syncthreads();
  if(wl==0 && lane<2){
    float o=b3[lane];
    for(int k=0;k<64;k++) o += r2[k]*w3[k*2+lane];
    out[g*2+lane]=o;
  }
}

extern "C" void kernel_launch(void* const* d_in, const int* in_sizes, int n_in,
                              void* d_out, int out_size, void* d_ws, size_t ws_size,
                              hipStream_t stream){
  const float* nf     = (const float*)d_in[0];
  const float* coords = (const float*)d_in[1];
  const int*   ei     = (const int*)d_in[2];
  const float* ef     = (const float*)d_in[3];
  const int*   batch  = (const int*)d_in[4];

  const float* enc_w1 = (const float*)d_in[5];
  const float* enc_b1 = (const float*)d_in[6];
  const float* enc_w2 = (const float*)d_in[7];
  const float* enc_b2 = (const float*)d_in[8];
  const float* pe_w1  = (const float*)d_in[9];
  const float* pe_b1  = (const float*)d_in[10];
  const float* pe_w2  = (const float*)d_in[11];
  const float* pe_b2  = (const float*)d_in[12];
  const float* ph_w1  = (const float*)d_in[13];
  const float* ph_b1  = (const float*)d_in[14];
  const float* ph_w2  = (const float*)d_in[15];
  const float* ph_b2  = (const float*)d_in[16];
  const float* px_w1  = (const float*)d_in[17];
  const float* px_b1  = (const float*)d_in[18];
  const float* px_w2  = (const float*)d_in[19];
  const float* px_b2  = (const float*)d_in[20];
  const float* ln_g   = (const float*)d_in[21];
  const float* ln_b   = (const float*)d_in[22];
  const float* ro_w1  = (const float*)d_in[23];
  const float* ro_b1  = (const float*)d_in[24];
  const float* ro_w2  = (const float*)d_in[25];
  const float* ro_b2  = (const float*)d_in[26];
  const float* ro_w3  = (const float*)d_in[27];
  const float* ro_b3  = (const float*)d_in[28];

  char* wsb = (char*)d_ws;
  size_t off = 0;
  auto alloc_f = [&](size_t nfl)->float*{ float* p=(float*)(wsb+off); off+=nfl*4; return p; };
  auto alloc_i = [&](size_t nin)->int*  { int*   p=(int*)(wsb+off);   off+=nin*4; return p; };

  float* h      = alloc_f((size_t)NN*128);
  float* x      = alloc_f((size_t)NN*3);
  float* agg    = alloc_f((size_t)NN*64);
  float* cacc   = alloc_f((size_t)NN*3);
  float* cntinv = alloc_f(NN);
  float* pa     = alloc_f((size_t)NN*64);
  float* pb     = alloc_f((size_t)NN*64);
  float* wvs    = alloc_f(NE);
  float* ef_s   = alloc_f((size_t)NE*16);
  int2*  sd_s   = (int2*)alloc_i((size_t)NE*2);
  int* roff_dst = alloc_i(NN+1);
  int* roff_src = alloc_i(NN+1);
  int* dlist    = alloc_i(NE);
  int* slist    = alloc_i(NE);
  int* bsum     = alloc_i(256);
  int* bbase    = alloc_i(256);
  int* cnt_dst  = alloc_i(NN);   // cnt_dst..cur_src contiguous -> one memset
  int* cnt_src  = alloc_i(NN);
  int* cur_dst  = alloc_i(NN);
  int* cur_src  = alloc_i(NN);

  hipMemsetAsync(cnt_dst, 0, (size_t)4*NN*sizeof(int), stream);
  k_degrees<<<(NE+255)/256,256,0,stream>>>(ei, cnt_dst, cnt_src);
  k_scan1<<<NB_SCAN,256,0,stream>>>(cnt_dst, roff_dst, bsum);
  k_scan2<<<1,256,0,stream>>>(bsum, bbase, roff_dst);
  k_scan3<<<NB_SCAN,256,0,stream>>>(roff_dst, bbase);
  k_scan1<<<NB_SCAN,256,0,stream>>>(cnt_src, roff_src, bsum);
  k_scan2<<<1,256,0,stream>>>(bsum, bbase, roff_src);
  k_scan3<<<NB_SCAN,256,0,stream>>>(roff_src, bbase);
  k_fill<<<(NE+255)/256,256,0,stream>>>(ei, roff_dst, roff_src, cur_dst, cur_src, dlist, slist);
  k_gather<<<(NE+255)/256,256,0,stream>>>(ei, ef, dlist, sd_s, ef_s);
  k_prep<<<(NN+255)/256,256,0,stream>>>(coords, cnt_dst, x, cntinv);
  k_encoder<<<(NN+31)/32,256,0,stream>>>(nf, enc_w1, enc_b1, enc_w2, enc_b2, h);

  int G  = (NE+EB-1)/EB;
  int G8 = ((G+7)/8)*8;

  for(int l=0;l<NL;l++){
    k_pre<<<(NN+31)/32,256,0,stream>>>(h, pe_w1+(size_t)l*273*64, pe_b1+l*64, pa, pb);
    hipMemsetAsync(agg, 0, (size_t)NN*64*sizeof(float), stream);
    k_edge2<<<G8,256,0,stream>>>(sd_s, ef_s, x, pa, pb, roff_dst,
        pe_w1+(size_t)l*273*64,
        pe_w2+(size_t)l*64*64, pe_b2+l*64,
        px_w1+(size_t)l*64*64, px_b1+l*64,
        px_w2+l*64, px_b2+l,
        agg, wvs);
    k_coordC<<<(NN+15)/16,256,0,stream>>>(sd_s, roff_src, slist, wvs, x, cacc);
    k_node<<<(NN+31)/32,256,0,stream>>>(agg, cacc, cntinv,
        ph_w1+(size_t)l*192*128, ph_b1+l*128,
        ph_w2+(size_t)l*128*128, ph_b2+l*128,
        ln_g+l*128, ln_b+l*128, h, x);
  }

  k_readout<<<NG,256,0,stream>>>(batch, h,
      ro_w1, ro_b1, ro_w2, ro_b2, ro_w3, ro_b3, (float*)d_out);
}

// Round 10
// 3262.125 us; speedup vs baseline: 1.5604x; 1.0149x over previous
//
#include <hip/hip_runtime.h>
#include <hip/hip_bf16.h>

#define NN 50000
#define NE 1000000
#define NG 256
#define NL 6
#define NB_SCAN 196   // ceil(NN/256)
#define EB 128        // edges per block in k_edge2

typedef float v2f __attribute__((ext_vector_type(2)));

__device__ __forceinline__ float siluf(float v){ return v / (1.0f + __expf(-v)); }

// ---- degree counts ----
__global__ void k_degrees(const int* __restrict__ ei, int* __restrict__ cnt_dst,
                          int* __restrict__ cnt_src){
  int e = blockIdx.x*256 + threadIdx.x;
  if (e<NE){
    atomicAdd(&cnt_dst[ei[NE+e]], 1);
    atomicAdd(&cnt_src[ei[e]], 1);
  }
}

// ---- hierarchical scan ----
__global__ void k_scan1(const int* __restrict__ cnt, int* __restrict__ roff,
                        int* __restrict__ bsum){
  __shared__ int sd[256];
  int t=threadIdx.x; int i=blockIdx.x*256+t;
  int v=(i<NN)?cnt[i]:0;
  sd[t]=v; __syncthreads();
  #pragma unroll
  for(int off=1;off<256;off<<=1){
    int xv=(t>=off)?sd[t-off]:0; __syncthreads();
    sd[t]+=xv; __syncthreads();
  }
  if(i<NN) roff[i]=sd[t]-v;
  if(t==255) bsum[blockIdx.x]=sd[t];
}
__global__ void k_scan2(const int* __restrict__ bsum, int* __restrict__ bbase,
                        int* __restrict__ roff){
  __shared__ int sd[256];
  int t=threadIdx.x;
  int v=(t<NB_SCAN)?bsum[t]:0;
  sd[t]=v; __syncthreads();
  #pragma unroll
  for(int off=1;off<256;off<<=1){
    int xv=(t>=off)?sd[t-off]:0; __syncthreads();
    sd[t]+=xv; __syncthreads();
  }
  if(t<NB_SCAN) bbase[t]=sd[t]-v;
  if(t==255) roff[NN]=sd[t];
}
__global__ void k_scan3(int* __restrict__ roff, const int* __restrict__ bbase){
  int i=blockIdx.x*256+threadIdx.x;
  if(i<NN) roff[i]+=bbase[blockIdx.x];
}

// ---- scatter-fill: dlist = edge ids dst-sorted; slist = dst-sorted POSITIONS per src ----
__global__ void k_fill(const int* __restrict__ ei,
                       const int* __restrict__ roff_dst, const int* __restrict__ roff_src,
                       int* __restrict__ cur_dst, int* __restrict__ cur_src,
                       int* __restrict__ dlist, int* __restrict__ slist){
  int e = blockIdx.x*256 + threadIdx.x;
  if (e<NE){
    int d = ei[NE+e];
    int pd = roff_dst[d] + atomicAdd(&cur_dst[d],1);
    dlist[pd] = e;
    int s = ei[e];
    int ps = roff_src[s] + atomicAdd(&cur_src[s],1);
    slist[ps] = pd;
  }
}

// ---- one-time gather into dst-sorted order ----
__global__ void k_gather(const int* __restrict__ ei, const float* __restrict__ ef,
                         const int* __restrict__ dlist,
                         int2* __restrict__ sd_s, float* __restrict__ ef_s){
  int p = blockIdx.x*256 + threadIdx.x;
  if (p<NE){
    int e = dlist[p];
    sd_s[p] = make_int2(ei[e], ei[NE+e]);
    const float4* src = (const float4*)(ef + (size_t)e*16);
    float4* dst = (float4*)(ef_s + (size_t)p*16);
    dst[0]=src[0]; dst[1]=src[1]; dst[2]=src[2]; dst[3]=src[3];
  }
}

// ---- init coords + 1/max(indeg,1) ----
__global__ void k_prep(const float* __restrict__ coords,
                       const int* __restrict__ cnt,
                       float* __restrict__ x, float* __restrict__ cntinv){
  int n = blockIdx.x*256+threadIdx.x;
  if (n<NN){
    x[n*3+0]=coords[n*3+0];
    x[n*3+1]=coords[n*3+1];
    x[n*3+2]=coords[n*3+2];
    cntinv[n]=1.0f/fmaxf((float)cnt[n],1.0f);
  }
}

// ==== tiled encoder ====
__global__ void __launch_bounds__(256)
k_encoder(const float* __restrict__ nf,
          const float* __restrict__ w1, const float* __restrict__ b1,
          const float* __restrict__ w2, const float* __restrict__ b2,
          float* __restrict__ h){
  __shared__ float in1[32][17];
  __shared__ float t1[32][129];
  __shared__ float wt[16][136];
  int tid=threadIdx.x;
  int g0=blockIdx.x*32;
  int ty=tid>>4, tx=tid&15;
  int n0=ty*2, n1=ty*2+1;
  { int n=tid>>3, c=(tid&7)*2;
    int gn=g0+n; if(gn>=NN) gn=NN-1;
    float2 v=*(const float2*)(nf+(size_t)gn*16+c);
    in1[n][c]=v.x; in1[n][c+1]=v.y; }
  { int c=tx*8;
    const float* src=w1+(size_t)ty*128+c;
    *(float4*)&wt[ty][c]  =*(const float4*)src;
    *(float4*)&wt[ty][c+4]=*(const float4*)(src+4); }
  __syncthreads();
  float4 a00,a01,a10,a11;
  a00=*(const float4*)(b1+tx*8); a01=*(const float4*)(b1+tx*8+4);
  a10=a00; a11=a01;
  #pragma unroll
  for(int k=0;k<16;k++){
    float m0=in1[n0][k], m1=in1[n1][k];
    float4 wa=*(float4*)&wt[k][tx*8], wb=*(float4*)&wt[k][tx*8+4];
    a00.x+=m0*wa.x; a00.y+=m0*wa.y; a00.z+=m0*wa.z; a00.w+=m0*wa.w;
    a01.x+=m0*wb.x; a01.y+=m0*wb.y; a01.z+=m0*wb.z; a01.w+=m0*wb.w;
    a10.x+=m1*wa.x; a10.y+=m1*wa.y; a10.z+=m1*wa.z; a10.w+=m1*wa.w;
    a11.x+=m1*wb.x; a11.y+=m1*wb.y; a11.z+=m1*wb.z; a11.w+=m1*wb.w;
  }
  int c8=tx*8;
  t1[n0][c8+0]=siluf(a00.x); t1[n0][c8+1]=siluf(a00.y); t1[n0][c8+2]=siluf(a00.z); t1[n0][c8+3]=siluf(a00.w);
  t1[n0][c8+4]=siluf(a01.x); t1[n0][c8+5]=siluf(a01.y); t1[n0][c8+6]=siluf(a01.z); t1[n0][c8+7]=siluf(a01.w);
  t1[n1][c8+0]=siluf(a10.x); t1[n1][c8+1]=siluf(a10.y); t1[n1][c8+2]=siluf(a10.z); t1[n1][c8+3]=siluf(a10.w);
  t1[n1][c8+4]=siluf(a11.x); t1[n1][c8+5]=siluf(a11.y); t1[n1][c8+6]=siluf(a11.z); t1[n1][c8+7]=siluf(a11.w);
  __syncthreads();
  a00=*(const float4*)(b2+c8); a01=*(const float4*)(b2+c8+4);
  a10=a00; a11=a01;
  for(int kt=0;kt<8;kt++){
    { const float* src=w2+(size_t)(kt*16+ty)*128+c8;
      *(float4*)&wt[ty][c8]  =*(const float4*)src;
      *(float4*)&wt[ty][c8+4]=*(const float4*)(src+4); }
    __syncthreads();
    #pragma unroll
    for(int kk=0;kk<16;kk++){
      int k=kt*16+kk;
      float m0=t1[n0][k], m1=t1[n1][k];
      float4 wa=*(float4*)&wt[kk][c8], wb=*(float4*)&wt[kk][c8+4];
      a00.x+=m0*wa.x; a00.y+=m0*wa.y; a00.z+=m0*wa.z; a00.w+=m0*wa.w;
      a01.x+=m0*wb.x; a01.y+=m0*wb.y; a01.z+=m0*wb.z; a01.w+=m0*wb.w;
      a10.x+=m1*wa.x; a10.y+=m1*wa.y; a10.z+=m1*wa.z; a10.w+=m1*wa.w;
      a11.x+=m1*wb.x; a11.y+=m1*wb.y; a11.z+=m1*wb.z; a11.w+=m1*wb.w;
    }
    __syncthreads();
  }
  int gn0=g0+n0, gn1=g0+n1;
  if(gn0<NN){ *(float4*)(h+(size_t)gn0*128+c8)=a00; *(float4*)(h+(size_t)gn0*128+c8+4)=a01; }
  if(gn1<NN){ *(float4*)(h+(size_t)gn1*128+c8)=a10; *(float4*)(h+(size_t)gn1*128+c8+4)=a11; }
}

// ==== tiled k_pre (every layer) ====
__global__ void __launch_bounds__(256)
k_pre(const float* __restrict__ h,
      const float* __restrict__ w1, const float* __restrict__ b1,
      float* __restrict__ pa, float* __restrict__ pb){
  __shared__ float hs[32][129];
  __shared__ float wt[16][136];
  int tid=threadIdx.x;
  int g0=blockIdx.x*32;
  int ty=tid>>4, tx=tid&15;
  int n0=ty*2, n1=ty*2+1;
  { int n=tid>>3, c0=(tid&7)*16;
    int gn=g0+n; if(gn>=NN) gn=NN-1;
    const float* src=h+(size_t)gn*128+c0;
    #pragma unroll
    for(int q=0;q<4;q++){
      float4 v=*(const float4*)(src+q*4);
      hs[n][c0+q*4]=v.x; hs[n][c0+q*4+1]=v.y; hs[n][c0+q*4+2]=v.z; hs[n][c0+q*4+3]=v.w;
    } }
  int c8=tx*8;
  float4 a00,a01,a10,a11;
  if(tx<8){ a00=*(const float4*)(b1+c8); a01=*(const float4*)(b1+c8+4); }
  else    { a00=make_float4(0,0,0,0); a01=a00; }
  a10=a00; a11=a01;
  for(int kt=0;kt<8;kt++){
    { int grow=(tx<8)?(kt*16+ty):(128+kt*16+ty);
      int gcol=(tx&7)*8;
      const float* src=w1+(size_t)grow*64+gcol;
      *(float4*)&wt[ty][c8]  =*(const float4*)src;
      *(float4*)&wt[ty][c8+4]=*(const float4*)(src+4); }
    __syncthreads();
    #pragma unroll
    for(int kk=0;kk<16;kk++){
      int k=kt*16+kk;
      float m0=hs[n0][k], m1=hs[n1][k];
      float4 wa=*(float4*)&wt[kk][c8], wb=*(float4*)&wt[kk][c8+4];
      a00.x+=m0*wa.x; a00.y+=m0*wa.y; a00.z+=m0*wa.z; a00.w+=m0*wa.w;
      a01.x+=m0*wb.x; a01.y+=m0*wb.y; a01.z+=m0*wb.z; a01.w+=m0*wb.w;
      a10.x+=m1*wa.x; a10.y+=m1*wa.y; a10.z+=m1*wa.z; a10.w+=m1*wa.w;
      a11.x+=m1*wb.x; a11.y+=m1*wb.y; a11.z+=m1*wb.z; a11.w+=m1*wb.w;
    }
    __syncthreads();
  }
  int gn0=g0+n0, gn1=g0+n1;
  float* base0 = (tx<8)? (pa+(size_t)gn0*64+c8) : (pb+(size_t)gn0*64+(c8-64));
  float* base1 = (tx<8)? (pa+(size_t)gn1*64+c8) : (pb+(size_t)gn1*64+(c8-64));
  if(gn0<NN){ *(float4*)base0=a00; *(float4*)(base0+4)=a01; }
  if(gn1<NN){ *(float4*)base1=a10; *(float4*)(base1+4)=a11; }
}

// ==== fused edge kernel — 512 threads, 4 threads/edge (16 cols each) ====
__global__ void __launch_bounds__(512,8)
k_edge2(const int2* __restrict__ sd, const float* __restrict__ efs,
        const float* __restrict__ x,
        const float* __restrict__ pa, const float* __restrict__ pb,
        const int* __restrict__ roff_dst,
        const float* __restrict__ w1,
        const float* __restrict__ w2, const float* __restrict__ b2,
        const float* __restrict__ xw1, const float* __restrict__ xb1,
        const float* __restrict__ xw2, const float* __restrict__ xb2,
        float* __restrict__ agg, float* __restrict__ wvs){
  __shared__ float tls[EB*65];
  __shared__ float wvp4[4][EB];
  int bid = blockIdx.x;
  int nb = (bid&7)*((int)gridDim.x>>3) + (bid>>3);
  int p0 = nb*EB;
  if (p0 >= NE) return;
  int tid = threadIdx.x;
  int wl = tid>>6, lane = tid&63;
  int eidx = (wl&1)*64 + lane;                       // 0..127
  int quarter = wl>>1;                               // 0..3, wave-uniform
  int c0 = __builtin_amdgcn_readfirstlane(quarter*16);
  int p  = p0 + eidx;
  bool valid = (p < NE);
  v2f acc[8];
  float part = 0.f;
  if (valid){
    int2 sdp = sd[p];
    int s = sdp.x, d = sdp.y;
    float dx = x[s*3+0]-x[d*3+0];
    float dy = x[s*3+1]-x[d*3+1];
    float dz = x[s*3+2]-x[d*3+2];
    float sq = dx*dx+dy*dy+dz*dz;
    const float4* pa4 = (const float4*)(pa + (size_t)s*64 + c0);
    const float4* pb4 = (const float4*)(pb + (size_t)d*64 + c0);
    #pragma unroll
    for(int q=0;q<4;q++){
      float4 A=pa4[q], B=pb4[q];
      v2f lo = {A.x+B.x, A.y+B.y};
      v2f hi = {A.z+B.z, A.w+B.w};
      acc[q*2+0]=lo; acc[q*2+1]=hi;
    }
    { const v2f* wr = (const v2f*)(w1 + 256*64 + c0);
      v2f sq2 = {sq, sq};
      #pragma unroll
      for(int j=0;j<8;j++) acc[j] += sq2*wr[j]; }
    { const float4* efp=(const float4*)(efs+(size_t)p*16);
      #pragma unroll
      for(int k4=0;k4<4;k4++){
        float4 m4=efp[k4];
        float mv[4]={m4.x,m4.y,m4.z,m4.w};
        #pragma unroll
        for(int kk=0;kk<4;kk++){
          const v2f* wr = (const v2f*)(w1 + (257+k4*4+kk)*64 + c0);
          v2f m2 = {mv[kk], mv[kk]};
          #pragma unroll
          for(int j=0;j<8;j++) acc[j]+=m2*wr[j];
        }
      } }
    #pragma unroll
    for(int j=0;j<8;j++){
      tls[eidx*65+c0+2*j]   = siluf(acc[j].x);
      tls[eidx*65+c0+2*j+1] = siluf(acc[j].y);
    }
  }
  __syncthreads();                 // t complete
  if (valid){
    { const v2f* b2v=(const v2f*)(b2+c0);
      #pragma unroll
      for(int j=0;j<8;j++) acc[j]=b2v[j]; }
    for(int k=0;k<64;k++){
      float m = tls[eidx*65+k];
      const v2f* wr = (const v2f*)(w2 + k*64 + c0);
      v2f m2 = {m, m};
      #pragma unroll
      for(int j=0;j<8;j++) acc[j] += m2*wr[j];
    }
    #pragma unroll
    for(int j=0;j<8;j++){ acc[j].x=siluf(acc[j].x); acc[j].y=siluf(acc[j].y); }
  }
  __syncthreads();                 // all t reads done
  if (valid){
    #pragma unroll
    for(int j=0;j<8;j++){
      tls[eidx*65+c0+2*j]   = acc[j].x;
      tls[eidx*65+c0+2*j+1] = acc[j].y;
    }
  }
  __syncthreads();                 // msg complete
  if (valid){
    { const v2f* xbv=(const v2f*)(xb1+c0);
      #pragma unroll
      for(int j=0;j<8;j++) acc[j]=xbv[j]; }
    for(int k=0;k<64;k++){
      float m = tls[eidx*65+k];
      const v2f* wr = (const v2f*)(xw1 + k*64 + c0);
      v2f m2 = {m, m};
      #pragma unroll
      for(int j=0;j<8;j++) acc[j]+=m2*wr[j];
    }
    const float* xw2c = xw2 + c0;
    #pragma unroll
    for(int j=0;j<8;j++) part += siluf(acc[j].x)*xw2c[2*j] + siluf(acc[j].y)*xw2c[2*j+1];
    wvp4[quarter][eidx] = part;
  }
  __syncthreads();                 // wvp4 + msg final
  int pend = (p0+EB < NE) ? (p0+EB) : NE;
  if (valid && wl < 2)             // waves 0,1 cover eidx 0..127 once
    wvs[p] = wvp4[0][eidx]+wvp4[1][eidx]+wvp4[2][eidx]+wvp4[3][eidx] + xb2[0];
  // fused segmented reduction over dst; exclusive segments use plain stores
  int dfirst = sd[p0].y;
  int dlast  = sd[pend-1].y;
  int j = tid&63, slot = tid>>6;
  for (int n=dfirst+slot; n<=dlast; n+=8){
    int rs0 = roff_dst[n], re0 = roff_dst[n+1];
    int rs = (rs0 > p0)   ? rs0 : p0;
    int re = (re0 < pend) ? re0 : pend;
    rs -= p0; re -= p0;
    if (re > rs){
      float sum=0.f;
      for (int r=rs; r<re; r++) sum += tls[r*65+j];
      if (rs0 >= p0 && re0 <= pend) agg[(size_t)n*64+j] = sum;      // exclusive
      else                          atomicAdd(&agg[(size_t)n*64+j], sum);
    }
  }
}

// ---- phase C: 16 lanes per src node ----
__global__ void k_coordC(const int2* __restrict__ sd,
                         const int* __restrict__ roff_src, const int* __restrict__ slist,
                         const float* __restrict__ wvs, const float* __restrict__ x,
                         float* __restrict__ cacc){
  int tid=threadIdx.x;
  int grp=tid>>4, sub=tid&15;
  int n = blockIdx.x*16 + grp;
  if (n >= NN) return;
  int s = roff_src[n], e2 = roff_src[n+1];
  float xs0=x[n*3+0], xs1=x[n*3+1], xs2=x[n*3+2];
  float a0=0.f, a1=0.f, a2=0.f;
  for (int p=s+sub; p<e2; p+=16){
    int q = slist[p];
    float w = wvs[q];
    int d = sd[q].y;
    a0 += (xs0 - x[d*3+0])*w;
    a1 += (xs1 - x[d*3+1])*w;
    a2 += (xs2 - x[d*3+2])*w;
  }
  #pragma unroll
  for(int off=1; off<16; off<<=1){
    a0 += __shfl_xor(a0, off);
    a1 += __shfl_xor(a1, off);
    a2 += __shfl_xor(a2, off);
  }
  if (sub==0){
    cacc[n*3+0]=a0; cacc[n*3+1]=a1; cacc[n*3+2]=a2;
  }
}

// ==== tiled k_node ====
__global__ void __launch_bounds__(256)
k_node(const float* __restrict__ agg, const float* __restrict__ cacc,
       const float* __restrict__ cntinv,
       const float* __restrict__ hw1, const float* __restrict__ hb1,
       const float* __restrict__ hw2, const float* __restrict__ hb2,
       const float* __restrict__ lng, const float* __restrict__ lnb,
       float* __restrict__ h, float* __restrict__ x){
  __shared__ float cat[32][193];
  __shared__ float t1[32][129];
  __shared__ float wt[16][136];
  __shared__ float psA[32][8], psB[32][8];
  __shared__ float mu_s[32], rs_s[32];
  int tid=threadIdx.x;
  int g0=blockIdx.x*32;
  int ty=tid>>4, tx=tid&15;
  int n0=ty*2, n1=ty*2+1;
  int c8=tx*8;
  { int n=tid>>3, c0=(tid&7)*16;
    int gn=g0+n; if(gn>=NN) gn=NN-1;
    float ci = cntinv[gn];
    const float* src=h+(size_t)gn*128+c0;
    #pragma unroll
    for(int q=0;q<4;q++){
      float4 v=*(const float4*)(src+q*4);
      cat[n][c0+q*4]=v.x; cat[n][c0+q*4+1]=v.y; cat[n][c0+q*4+2]=v.z; cat[n][c0+q*4+3]=v.w;
    }
    int ca=(tid&7)*8;
    const float* srca=agg+(size_t)gn*64+ca;
    #pragma unroll
    for(int q=0;q<2;q++){
      float4 v=*(const float4*)(srca+q*4);
      cat[n][128+ca+q*4]=v.x*ci; cat[n][128+ca+q*4+1]=v.y*ci;
      cat[n][128+ca+q*4+2]=v.z*ci; cat[n][128+ca+q*4+3]=v.w*ci;
    } }
  float4 a00=*(const float4*)(hb1+c8), a01=*(const float4*)(hb1+c8+4);
  float4 a10=a00, a11=a01;
  for(int kt=0;kt<12;kt++){
    { const float* src=hw1+(size_t)(kt*16+ty)*128+c8;
      *(float4*)&wt[ty][c8]  =*(const float4*)src;
      *(float4*)&wt[ty][c8+4]=*(const float4*)(src+4); }
    __syncthreads();
    #pragma unroll
    for(int kk=0;kk<16;kk++){
      int k=kt*16+kk;
      float m0=cat[n0][k], m1=cat[n1][k];
      float4 wa=*(float4*)&wt[kk][c8], wb=*(float4*)&wt[kk][c8+4];
      a00.x+=m0*wa.x; a00.y+=m0*wa.y; a00.z+=m0*wa.z; a00.w+=m0*wa.w;
      a01.x+=m0*wb.x; a01.y+=m0*wb.y; a01.z+=m0*wb.z; a01.w+=m0*wb.w;
      a10.x+=m1*wa.x; a10.y+=m1*wa.y; a10.z+=m1*wa.z; a10.w+=m1*wa.w;
      a11.x+=m1*wb.x; a11.y+=m1*wb.y; a11.z+=m1*wb.z; a11.w+=m1*wb.w;
    }
    __syncthreads();
  }
  t1[n0][c8+0]=siluf(a00.x); t1[n0][c8+1]=siluf(a00.y); t1[n0][c8+2]=siluf(a00.z); t1[n0][c8+3]=siluf(a00.w);
  t1[n0][c8+4]=siluf(a01.x); t1[n0][c8+5]=siluf(a01.y); t1[n0][c8+6]=siluf(a01.z); t1[n0][c8+7]=siluf(a01.w);
  t1[n1][c8+0]=siluf(a10.x); t1[n1][c8+1]=siluf(a10.y); t1[n1][c8+2]=siluf(a10.z); t1[n1][c8+3]=siluf(a10.w);
  t1[n1][c8+4]=siluf(a11.x); t1[n1][c8+5]=siluf(a11.y); t1[n1][c8+6]=siluf(a11.z); t1[n1][c8+7]=siluf(a11.w);
  __syncthreads();
  a00=*(const float4*)(hb2+c8); a01=*(const float4*)(hb2+c8+4);
  a10=a00; a11=a01;
  for(int kt=0;kt<8;kt++){
    { const float* src=hw2+(size_t)(kt*16+ty)*128+c8;
      *(float4*)&wt[ty][c8]  =*(const float4*)src;
      *(float4*)&wt[ty][c8+4]=*(const float4*)(src+4); }
    __syncthreads();
    #pragma unroll
    for(int kk=0;kk<16;kk++){
      int k=kt*16+kk;
      float m0=t1[n0][k], m1=t1[n1][k];
      float4 wa=*(float4*)&wt[kk][c8], wb=*(float4*)&wt[kk][c8+4];
      a00.x+=m0*wa.x; a00.y+=m0*wa.y; a00.z+=m0*wa.z; a00.w+=m0*wa.w;
      a01.x+=m0*wb.x; a01.y+=m0*wb.y; a01.z+=m0*wb.z; a01.w+=m0*wb.w;
      a10.x+=m1*wa.x; a10.y+=m1*wa.y; a10.z+=m1*wa.z; a10.w+=m1*wa.w;
      a11.x+=m1*wb.x; a11.y+=m1*wb.y; a11.z+=m1*wb.z; a11.w+=m1*wb.w;
    }
    __syncthreads();
  }
  cat[n0][c8+0]+=a00.x; cat[n0][c8+1]+=a00.y; cat[n0][c8+2]+=a00.z; cat[n0][c8+3]+=a00.w;
  cat[n0][c8+4]+=a01.x; cat[n0][c8+5]+=a01.y; cat[n0][c8+6]+=a01.z; cat[n0][c8+7]+=a01.w;
  cat[n1][c8+0]+=a10.x; cat[n1][c8+1]+=a10.y; cat[n1][c8+2]+=a10.z; cat[n1][c8+3]+=a10.w;
  cat[n1][c8+4]+=a11.x; cat[n1][c8+5]+=a11.y; cat[n1][c8+6]+=a11.z; cat[n1][c8+7]+=a11.w;
  __syncthreads();
  { int rid=tid>>3, sub=tid&7;
    float sm=0.f, ss=0.f;
    #pragma unroll
    for(int i=0;i<16;i++){ float v=cat[rid][sub*16+i]; sm+=v; ss+=v*v; }
    psA[rid][sub]=sm; psB[rid][sub]=ss; }
  __syncthreads();
  { int rid=tid>>3, sub=tid&7;
    if(sub==0){
      float sm=0.f, ss=0.f;
      #pragma unroll
      for(int i=0;i<8;i++){ sm+=psA[rid][i]; ss+=psB[rid][i]; }
      float mu=sm*(1.0f/128.0f);
      float var=ss*(1.0f/128.0f)-mu*mu;
      mu_s[rid]=mu; rs_s[rid]=rsqrtf(fmaxf(var,0.0f)+1e-5f);
    } }
  __syncthreads();
  { int rid=tid>>3, sub=tid&7;
    int gn=g0+rid;
    if(gn<NN){
      float mu=mu_s[rid], rs=rs_s[rid];
      int c0=sub*16;
      #pragma unroll
      for(int q=0;q<4;q++){
        float4 g4=*(const float4*)(lng+c0+q*4);
        float4 b4=*(const float4*)(lnb+c0+q*4);
        float4 o;
        o.x=(cat[rid][c0+q*4+0]-mu)*rs*g4.x+b4.x;
        o.y=(cat[rid][c0+q*4+1]-mu)*rs*g4.y+b4.y;
        o.z=(cat[rid][c0+q*4+2]-mu)*rs*g4.z+b4.z;
        o.w=(cat[rid][c0+q*4+3]-mu)*rs*g4.w+b4.w;
        *(float4*)(h+(size_t)gn*128+c0+q*4)=o;
      }
    } }
  if(tid<32){
    int gn=g0+tid;
    if(gn<NN){
      float ci=cntinv[gn];
      x[gn*3+0]+=cacc[gn*3+0]*ci;
      x[gn*3+1]+=cacc[gn*3+1]*ci;
      x[gn*3+2]+=cacc[gn*3+2]*ci;
    }
  }
}

// ---- readout ----
__device__ __forceinline__ int lowerb(const int* a, int n, int v){
  int lo=0, hi=n;
  while(lo<hi){ int mid=(lo+hi)>>1; if(a[mid]<v) lo=mid+1; else hi=mid; }
  return lo;
}

__global__ void k_readout(const int* __restrict__ batch, const float* __restrict__ h,
                          const float* __restrict__ w1, const float* __restrict__ b1,
                          const float* __restrict__ w2, const float* __restrict__ b2,
                          const float* __restrict__ w3, const float* __restrict__ b3,
                          float* __restrict__ out){
  int g = blockIdx.x;
  int wl = threadIdx.x>>6, lane = threadIdx.x&63;
  __shared__ float part[4][128];
  __shared__ float gh[128];
  __shared__ float r1[128];
  __shared__ float r2[64];
  int start = lowerb(batch, NN, g);
  int end   = lowerb(batch, NN, g+1);
  float s0=0.f, s1=0.f;
  for(int n=start+wl; n<end; n+=4){
    s0 += h[(size_t)n*128+2*lane];
    s1 += h[(size_t)n*128+2*lane+1];
  }
  part[wl][2*lane]=s0; part[wl][2*lane+1]=s1;
  __syncthreads();
  float ci = 1.0f/fmaxf((float)(end-start),1.0f);
  if(wl==0){
    gh[2*lane]   = (part[0][2*lane]+part[1][2*lane]+part[2][2*lane]+part[3][2*lane])*ci;
    gh[2*lane+1] = (part[0][2*lane+1]+part[1][2*lane+1]+part[2][2*lane+1]+part[3][2*lane+1])*ci;
  }
  __syncthreads();
  if(wl==0){
    float a0=b1[2*lane], a1=b1[2*lane+1];
    for(int k=0;k<128;k++){
      float m=gh[k];
      float2 w=((const float2*)(w1+k*128))[lane];
      a0+=m*w.x; a1+=m*w.y;
    }
    r1[2*lane]=siluf(a0); r1[2*lane+1]=siluf(a1);
  }
  __syncthreads();
  if(wl==0){
    float b=b2[lane];
    for(int k=0;k<128;k++) b += r1[k]*w2[k*64+lane];
    r2[lane]=siluf(b);
  }
  __syncthreads();
  if(wl==0 && lane<2){
    float o=b3[lane];
    for(int k=0;k<64;k++) o += r2[k]*w3[k*2+lane];
    out[g*2+lane]=o;
  }
}

extern "C" void kernel_launch(void* const* d_in, const int* in_sizes, int n_in,
                              void* d_out, int out_size, void* d_ws, size_t ws_size,
                              hipStream_t stream){
  const float* nf     = (const float*)d_in[0];
  const float* coords = (const float*)d_in[1];
  const int*   ei     = (const int*)d_in[2];
  const float* ef     = (const float*)d_in[3];
  const int*   batch  = (const int*)d_in[4];

  const float* enc_w1 = (const float*)d_in[5];
  const float* enc_b1 = (const float*)d_in[6];
  const float* enc_w2 = (const float*)d_in[7];
  const float* enc_b2 = (const float*)d_in[8];
  const float* pe_w1  = (const float*)d_in[9];
  const float* pe_b1  = (const float*)d_in[10];
  const float* pe_w2  = (const float*)d_in[11];
  const float* pe_b2  = (const float*)d_in[12];
  const float* ph_w1  = (const float*)d_in[13];
  const float* ph_b1  = (const float*)d_in[14];
  const float* ph_w2  = (const float*)d_in[15];
  const float* ph_b2  = (const float*)d_in[16];
  const float* px_w1  = (const float*)d_in[17];
  const float* px_b1  = (const float*)d_in[18];
  const float* px_w2  = (const float*)d_in[19];
  const float* px_b2  = (const float*)d_in[20];
  const float* ln_g   = (const float*)d_in[21];
  const float* ln_b   = (const float*)d_in[22];
  const float* ro_w1  = (const float*)d_in[23];
  const float* ro_b1  = (const float*)d_in[24];
  const float* ro_w2  = (const float*)d_in[25];
  const float* ro_b2  = (const float*)d_in[26];
  const float* ro_w3  = (const float*)d_in[27];
  const float* ro_b3  = (const float*)d_in[28];

  char* wsb = (char*)d_ws;
  size_t off = 0;
  auto alloc_f = [&](size_t nfl)->float*{ float* p=(float*)(wsb+off); off+=nfl*4; return p; };
  auto alloc_i = [&](size_t nin)->int*  { int*   p=(int*)(wsb+off);   off+=nin*4; return p; };

  float* h      = alloc_f((size_t)NN*128);
  float* x      = alloc_f((size_t)NN*3);
  float* agg    = alloc_f((size_t)NN*64);
  float* cacc   = alloc_f((size_t)NN*3);
  float* cntinv = alloc_f(NN);
  float* pa     = alloc_f((size_t)NN*64);
  float* pb     = alloc_f((size_t)NN*64);
  float* wvs    = alloc_f(NE);
  float* ef_s   = alloc_f((size_t)NE*16);
  int2*  sd_s   = (int2*)alloc_i((size_t)NE*2);
  int* roff_dst = alloc_i(NN+1);
  int* roff_src = alloc_i(NN+1);
  int* dlist    = alloc_i(NE);
  int* slist    = alloc_i(NE);
  int* bsum     = alloc_i(256);
  int* bbase    = alloc_i(256);
  int* cnt_dst  = alloc_i(NN);   // cnt_dst..cur_src contiguous -> one memset
  int* cnt_src  = alloc_i(NN);
  int* cur_dst  = alloc_i(NN);
  int* cur_src  = alloc_i(NN);

  hipMemsetAsync(cnt_dst, 0, (size_t)4*NN*sizeof(int), stream);
  k_degrees<<<(NE+255)/256,256,0,stream>>>(ei, cnt_dst, cnt_src);
  k_scan1<<<NB_SCAN,256,0,stream>>>(cnt_dst, roff_dst, bsum);
  k_scan2<<<1,256,0,stream>>>(bsum, bbase, roff_dst);
  k_scan3<<<NB_SCAN,256,0,stream>>>(roff_dst, bbase);
  k_scan1<<<NB_SCAN,256,0,stream>>>(cnt_src, roff_src, bsum);
  k_scan2<<<1,256,0,stream>>>(bsum, bbase, roff_src);
  k_scan3<<<NB_SCAN,256,0,stream>>>(roff_src, bbase);
  k_fill<<<(NE+255)/256,256,0,stream>>>(ei, roff_dst, roff_src, cur_dst, cur_src, dlist, slist);
  k_gather<<<(NE+255)/256,256,0,stream>>>(ei, ef, dlist, sd_s, ef_s);
  k_prep<<<(NN+255)/256,256,0,stream>>>(coords, cnt_dst, x, cntinv);
  k_encoder<<<(NN+31)/32,256,0,stream>>>(nf, enc_w1, enc_b1, enc_w2, enc_b2, h);

  int G  = (NE+EB-1)/EB;
  int G8 = ((G+7)/8)*8;

  for(int l=0;l<NL;l++){
    k_pre<<<(NN+31)/32,256,0,stream>>>(h, pe_w1+(size_t)l*273*64, pe_b1+l*64, pa, pb);
    hipMemsetAsync(agg, 0, (size_t)NN*64*sizeof(float), stream);
    k_edge2<<<G8,512,0,stream>>>(sd_s, ef_s, x, pa, pb, roff_dst,
        pe_w1+(size_t)l*273*64,
        pe_w2+(size_t)l*64*64, pe_b2+l*64,
        px_w1+(size_t)l*64*64, px_b1+l*64,
        px_w2+l*64, px_b2+l,
        agg, wvs);
    k_coordC<<<(NN+15)/16,256,0,stream>>>(sd_s, roff_src, slist, wvs, x, cacc);
    k_node<<<(NN+31)/32,256,0,stream>>>(agg, cacc, cntinv,
        ph_w1+(size_t)l*192*128, ph_b1+l*128,
        ph_w2+(size_t)l*128*128, ph_b2+l*128,
        ln_g+l*128, ln_b+l*128, h, x);
  }

  k_readout<<<NG,256,0,stream>>>(batch, h,
      ro_w1, ro_b1, ro_w2, ro_b2, ro_w3, ro_b3, (float*)d_out);
}

// Round 11
// 3117.000 us; speedup vs baseline: 1.6330x; 1.0466x over previous
//
#include <hip/hip_runtime.h>
#include <hip/hip_bf16.h>

#define NN 50000
#define NE 1000000
#define NG 256
#define NL 6
#define NB_SCAN 196   // ceil(NN/256)
#define EB 128        // edges per block in k_edge2

typedef float v2f __attribute__((ext_vector_type(2)));

// silu via hardware rcp (v_rcp_f32, ~1e-7 rel err) instead of refined fp32 divide
__device__ __forceinline__ float siluf(float v){
  return v * __builtin_amdgcn_rcpf(1.0f + __expf(-v));
}

// ---- degree counts ----
__global__ void k_degrees(const int* __restrict__ ei, int* __restrict__ cnt_dst,
                          int* __restrict__ cnt_src){
  int e = blockIdx.x*256 + threadIdx.x;
  if (e<NE){
    atomicAdd(&cnt_dst[ei[NE+e]], 1);
    atomicAdd(&cnt_src[ei[e]], 1);
  }
}

// ---- hierarchical scan ----
__global__ void k_scan1(const int* __restrict__ cnt, int* __restrict__ roff,
                        int* __restrict__ bsum){
  __shared__ int sd[256];
  int t=threadIdx.x; int i=blockIdx.x*256+t;
  int v=(i<NN)?cnt[i]:0;
  sd[t]=v; __syncthreads();
  #pragma unroll
  for(int off=1;off<256;off<<=1){
    int xv=(t>=off)?sd[t-off]:0; __syncthreads();
    sd[t]+=xv; __syncthreads();
  }
  if(i<NN) roff[i]=sd[t]-v;
  if(t==255) bsum[blockIdx.x]=sd[t];
}
__global__ void k_scan2(const int* __restrict__ bsum, int* __restrict__ bbase,
                        int* __restrict__ roff){
  __shared__ int sd[256];
  int t=threadIdx.x;
  int v=(t<NB_SCAN)?bsum[t]:0;
  sd[t]=v; __syncthreads();
  #pragma unroll
  for(int off=1;off<256;off<<=1){
    int xv=(t>=off)?sd[t-off]:0; __syncthreads();
    sd[t]+=xv; __syncthreads();
  }
  if(t<NB_SCAN) bbase[t]=sd[t]-v;
  if(t==255) roff[NN]=sd[t];
}
__global__ void k_scan3(int* __restrict__ roff, const int* __restrict__ bbase){
  int i=blockIdx.x*256+threadIdx.x;
  if(i<NN) roff[i]+=bbase[blockIdx.x];
}

// ---- scatter-fill: dlist = edge ids dst-sorted; slist = dst-sorted POSITIONS per src ----
__global__ void k_fill(const int* __restrict__ ei,
                       const int* __restrict__ roff_dst, const int* __restrict__ roff_src,
                       int* __restrict__ cur_dst, int* __restrict__ cur_src,
                       int* __restrict__ dlist, int* __restrict__ slist){
  int e = blockIdx.x*256 + threadIdx.x;
  if (e<NE){
    int d = ei[NE+e];
    int pd = roff_dst[d] + atomicAdd(&cur_dst[d],1);
    dlist[pd] = e;
    int s = ei[e];
    int ps = roff_src[s] + atomicAdd(&cur_src[s],1);
    slist[ps] = pd;
  }
}

// ---- one-time gather into dst-sorted order ----
__global__ void k_gather(const int* __restrict__ ei, const float* __restrict__ ef,
                         const int* __restrict__ dlist,
                         int2* __restrict__ sd_s, float* __restrict__ ef_s){
  int p = blockIdx.x*256 + threadIdx.x;
  if (p<NE){
    int e = dlist[p];
    sd_s[p] = make_int2(ei[e], ei[NE+e]);
    const float4* src = (const float4*)(ef + (size_t)e*16);
    float4* dst = (float4*)(ef_s + (size_t)p*16);
    dst[0]=src[0]; dst[1]=src[1]; dst[2]=src[2]; dst[3]=src[3];
  }
}

// ---- init coords + 1/max(indeg,1) ----
__global__ void k_prep(const float* __restrict__ coords,
                       const int* __restrict__ cnt,
                       float* __restrict__ x, float* __restrict__ cntinv){
  int n = blockIdx.x*256+threadIdx.x;
  if (n<NN){
    x[n*3+0]=coords[n*3+0];
    x[n*3+1]=coords[n*3+1];
    x[n*3+2]=coords[n*3+2];
    cntinv[n]=1.0f/fmaxf((float)cnt[n],1.0f);
  }
}

// ==== tiled encoder ====
__global__ void __launch_bounds__(256)
k_encoder(const float* __restrict__ nf,
          const float* __restrict__ w1, const float* __restrict__ b1,
          const float* __restrict__ w2, const float* __restrict__ b2,
          float* __restrict__ h){
  __shared__ float in1[32][17];
  __shared__ float t1[32][129];
  __shared__ float wt[16][136];
  int tid=threadIdx.x;
  int g0=blockIdx.x*32;
  int ty=tid>>4, tx=tid&15;
  int n0=ty*2, n1=ty*2+1;
  { int n=tid>>3, c=(tid&7)*2;
    int gn=g0+n; if(gn>=NN) gn=NN-1;
    float2 v=*(const float2*)(nf+(size_t)gn*16+c);
    in1[n][c]=v.x; in1[n][c+1]=v.y; }
  { int c=tx*8;
    const float* src=w1+(size_t)ty*128+c;
    *(float4*)&wt[ty][c]  =*(const float4*)src;
    *(float4*)&wt[ty][c+4]=*(const float4*)(src+4); }
  __syncthreads();
  float4 a00,a01,a10,a11;
  a00=*(const float4*)(b1+tx*8); a01=*(const float4*)(b1+tx*8+4);
  a10=a00; a11=a01;
  #pragma unroll
  for(int k=0;k<16;k++){
    float m0=in1[n0][k], m1=in1[n1][k];
    float4 wa=*(float4*)&wt[k][tx*8], wb=*(float4*)&wt[k][tx*8+4];
    a00.x+=m0*wa.x; a00.y+=m0*wa.y; a00.z+=m0*wa.z; a00.w+=m0*wa.w;
    a01.x+=m0*wb.x; a01.y+=m0*wb.y; a01.z+=m0*wb.z; a01.w+=m0*wb.w;
    a10.x+=m1*wa.x; a10.y+=m1*wa.y; a10.z+=m1*wa.z; a10.w+=m1*wa.w;
    a11.x+=m1*wb.x; a11.y+=m1*wb.y; a11.z+=m1*wb.z; a11.w+=m1*wb.w;
  }
  int c8=tx*8;
  t1[n0][c8+0]=siluf(a00.x); t1[n0][c8+1]=siluf(a00.y); t1[n0][c8+2]=siluf(a00.z); t1[n0][c8+3]=siluf(a00.w);
  t1[n0][c8+4]=siluf(a01.x); t1[n0][c8+5]=siluf(a01.y); t1[n0][c8+6]=siluf(a01.z); t1[n0][c8+7]=siluf(a01.w);
  t1[n1][c8+0]=siluf(a10.x); t1[n1][c8+1]=siluf(a10.y); t1[n1][c8+2]=siluf(a10.z); t1[n1][c8+3]=siluf(a10.w);
  t1[n1][c8+4]=siluf(a11.x); t1[n1][c8+5]=siluf(a11.y); t1[n1][c8+6]=siluf(a11.z); t1[n1][c8+7]=siluf(a11.w);
  __syncthreads();
  a00=*(const float4*)(b2+c8); a01=*(const float4*)(b2+c8+4);
  a10=a00; a11=a01;
  for(int kt=0;kt<8;kt++){
    { const float* src=w2+(size_t)(kt*16+ty)*128+c8;
      *(float4*)&wt[ty][c8]  =*(const float4*)src;
      *(float4*)&wt[ty][c8+4]=*(const float4*)(src+4); }
    __syncthreads();
    #pragma unroll
    for(int kk=0;kk<16;kk++){
      int k=kt*16+kk;
      float m0=t1[n0][k], m1=t1[n1][k];
      float4 wa=*(float4*)&wt[kk][c8], wb=*(float4*)&wt[kk][c8+4];
      a00.x+=m0*wa.x; a00.y+=m0*wa.y; a00.z+=m0*wa.z; a00.w+=m0*wa.w;
      a01.x+=m0*wb.x; a01.y+=m0*wb.y; a01.z+=m0*wb.z; a01.w+=m0*wb.w;
      a10.x+=m1*wa.x; a10.y+=m1*wa.y; a10.z+=m1*wa.z; a10.w+=m1*wa.w;
      a11.x+=m1*wb.x; a11.y+=m1*wb.y; a11.z+=m1*wb.z; a11.w+=m1*wb.w;
    }
    __syncthreads();
  }
  int gn0=g0+n0, gn1=g0+n1;
  if(gn0<NN){ *(float4*)(h+(size_t)gn0*128+c8)=a00; *(float4*)(h+(size_t)gn0*128+c8+4)=a01; }
  if(gn1<NN){ *(float4*)(h+(size_t)gn1*128+c8)=a10; *(float4*)(h+(size_t)gn1*128+c8+4)=a11; }
}

// ==== tiled k_pre (every layer) ====
__global__ void __launch_bounds__(256)
k_pre(const float* __restrict__ h,
      const float* __restrict__ w1, const float* __restrict__ b1,
      float* __restrict__ pa, float* __restrict__ pb){
  __shared__ float hs[32][129];
  __shared__ float wt[16][136];
  int tid=threadIdx.x;
  int g0=blockIdx.x*32;
  int ty=tid>>4, tx=tid&15;
  int n0=ty*2, n1=ty*2+1;
  { int n=tid>>3, c0=(tid&7)*16;
    int gn=g0+n; if(gn>=NN) gn=NN-1;
    const float* src=h+(size_t)gn*128+c0;
    #pragma unroll
    for(int q=0;q<4;q++){
      float4 v=*(const float4*)(src+q*4);
      hs[n][c0+q*4]=v.x; hs[n][c0+q*4+1]=v.y; hs[n][c0+q*4+2]=v.z; hs[n][c0+q*4+3]=v.w;
    } }
  int c8=tx*8;
  float4 a00,a01,a10,a11;
  if(tx<8){ a00=*(const float4*)(b1+c8); a01=*(const float4*)(b1+c8+4); }
  else    { a00=make_float4(0,0,0,0); a01=a00; }
  a10=a00; a11=a01;
  for(int kt=0;kt<8;kt++){
    { int grow=(tx<8)?(kt*16+ty):(128+kt*16+ty);
      int gcol=(tx&7)*8;
      const float* src=w1+(size_t)grow*64+gcol;
      *(float4*)&wt[ty][c8]  =*(const float4*)src;
      *(float4*)&wt[ty][c8+4]=*(const float4*)(src+4); }
    __syncthreads();
    #pragma unroll
    for(int kk=0;kk<16;kk++){
      int k=kt*16+kk;
      float m0=hs[n0][k], m1=hs[n1][k];
      float4 wa=*(float4*)&wt[kk][c8], wb=*(float4*)&wt[kk][c8+4];
      a00.x+=m0*wa.x; a00.y+=m0*wa.y; a00.z+=m0*wa.z; a00.w+=m0*wa.w;
      a01.x+=m0*wb.x; a01.y+=m0*wb.y; a01.z+=m0*wb.z; a01.w+=m0*wb.w;
      a10.x+=m1*wa.x; a10.y+=m1*wa.y; a10.z+=m1*wa.z; a10.w+=m1*wa.w;
      a11.x+=m1*wb.x; a11.y+=m1*wb.y; a11.z+=m1*wb.z; a11.w+=m1*wb.w;
    }
    __syncthreads();
  }
  int gn0=g0+n0, gn1=g0+n1;
  float* base0 = (tx<8)? (pa+(size_t)gn0*64+c8) : (pb+(size_t)gn0*64+(c8-64));
  float* base1 = (tx<8)? (pa+(size_t)gn1*64+c8) : (pb+(size_t)gn1*64+(c8-64));
  if(gn0<NN){ *(float4*)base0=a00; *(float4*)(base0+4)=a01; }
  if(gn1<NN){ *(float4*)base1=a10; *(float4*)(base1+4)=a11; }
}

// ==== fused edge kernel — 512 threads, 4 threads/edge (16 cols each) ====
__global__ void __launch_bounds__(512,8)
k_edge2(const int2* __restrict__ sd, const float* __restrict__ efs,
        const float* __restrict__ x,
        const float* __restrict__ pa, const float* __restrict__ pb,
        const int* __restrict__ roff_dst,
        const float* __restrict__ w1,
        const float* __restrict__ w2, const float* __restrict__ b2,
        const float* __restrict__ xw1, const float* __restrict__ xb1,
        const float* __restrict__ xw2, const float* __restrict__ xb2,
        float* __restrict__ agg, float* __restrict__ wvs){
  __shared__ float tls[EB*65];
  __shared__ float wvp4[4][EB];
  int bid = blockIdx.x;
  int nb = (bid&7)*((int)gridDim.x>>3) + (bid>>3);
  int p0 = nb*EB;
  if (p0 >= NE) return;
  int tid = threadIdx.x;
  int wl = tid>>6, lane = tid&63;
  int eidx = (wl&1)*64 + lane;                       // 0..127
  int quarter = wl>>1;                               // 0..3, wave-uniform
  int c0 = __builtin_amdgcn_readfirstlane(quarter*16);
  int p  = p0 + eidx;
  bool valid = (p < NE);
  v2f acc[8];
  float part = 0.f;
  if (valid){
    int2 sdp = sd[p];
    int s = sdp.x, d = sdp.y;
    float dx = x[s*3+0]-x[d*3+0];
    float dy = x[s*3+1]-x[d*3+1];
    float dz = x[s*3+2]-x[d*3+2];
    float sq = dx*dx+dy*dy+dz*dz;
    const float4* pa4 = (const float4*)(pa + (size_t)s*64 + c0);
    const float4* pb4 = (const float4*)(pb + (size_t)d*64 + c0);
    #pragma unroll
    for(int q=0;q<4;q++){
      float4 A=pa4[q], B=pb4[q];
      v2f lo = {A.x+B.x, A.y+B.y};
      v2f hi = {A.z+B.z, A.w+B.w};
      acc[q*2+0]=lo; acc[q*2+1]=hi;
    }
    { const v2f* wr = (const v2f*)(w1 + 256*64 + c0);
      v2f sq2 = {sq, sq};
      #pragma unroll
      for(int j=0;j<8;j++) acc[j] += sq2*wr[j]; }
    { const float4* efp=(const float4*)(efs+(size_t)p*16);
      #pragma unroll
      for(int k4=0;k4<4;k4++){
        float4 m4=efp[k4];
        float mv[4]={m4.x,m4.y,m4.z,m4.w};
        #pragma unroll
        for(int kk=0;kk<4;kk++){
          const v2f* wr = (const v2f*)(w1 + (257+k4*4+kk)*64 + c0);
          v2f m2 = {mv[kk], mv[kk]};
          #pragma unroll
          for(int j=0;j<8;j++) acc[j]+=m2*wr[j];
        }
      } }
    #pragma unroll
    for(int j=0;j<8;j++){
      tls[eidx*65+c0+2*j]   = siluf(acc[j].x);
      tls[eidx*65+c0+2*j+1] = siluf(acc[j].y);
    }
  }
  __syncthreads();                 // t complete
  if (valid){
    { const v2f* b2v=(const v2f*)(b2+c0);
      #pragma unroll
      for(int j=0;j<8;j++) acc[j]=b2v[j]; }
    for(int k=0;k<64;k++){
      float m = tls[eidx*65+k];
      const v2f* wr = (const v2f*)(w2 + k*64 + c0);
      v2f m2 = {m, m};
      #pragma unroll
      for(int j=0;j<8;j++) acc[j] += m2*wr[j];
    }
    #pragma unroll
    for(int j=0;j<8;j++){ acc[j].x=siluf(acc[j].x); acc[j].y=siluf(acc[j].y); }
  }
  __syncthreads();                 // all t reads done
  if (valid){
    #pragma unroll
    for(int j=0;j<8;j++){
      tls[eidx*65+c0+2*j]   = acc[j].x;
      tls[eidx*65+c0+2*j+1] = acc[j].y;
    }
  }
  __syncthreads();                 // msg complete
  if (valid){
    { const v2f* xbv=(const v2f*)(xb1+c0);
      #pragma unroll
      for(int j=0;j<8;j++) acc[j]=xbv[j]; }
    for(int k=0;k<64;k++){
      float m = tls[eidx*65+k];
      const v2f* wr = (const v2f*)(xw1 + k*64 + c0);
      v2f m2 = {m, m};
      #pragma unroll
      for(int j=0;j<8;j++) acc[j]+=m2*wr[j];
    }
    const float* xw2c = xw2 + c0;
    #pragma unroll
    for(int j=0;j<8;j++) part += siluf(acc[j].x)*xw2c[2*j] + siluf(acc[j].y)*xw2c[2*j+1];
    wvp4[quarter][eidx] = part;
  }
  __syncthreads();                 // wvp4 + msg final
  int pend = (p0+EB < NE) ? (p0+EB) : NE;
  if (valid && wl < 2)             // waves 0,1 cover eidx 0..127 once
    wvs[p] = wvp4[0][eidx]+wvp4[1][eidx]+wvp4[2][eidx]+wvp4[3][eidx] + xb2[0];
  // fused segmented reduction over dst; exclusive segments use plain stores
  int dfirst = sd[p0].y;
  int dlast  = sd[pend-1].y;
  int j = tid&63, slot = tid>>6;
  for (int n=dfirst+slot; n<=dlast; n+=8){
    int rs0 = roff_dst[n], re0 = roff_dst[n+1];
    int rs = (rs0 > p0)   ? rs0 : p0;
    int re = (re0 < pend) ? re0 : pend;
    rs -= p0; re -= p0;
    if (re > rs){
      float sum=0.f;
      for (int r=rs; r<re; r++) sum += tls[r*65+j];
      if (rs0 >= p0 && re0 <= pend) agg[(size_t)n*64+j] = sum;      // exclusive
      else                          atomicAdd(&agg[(size_t)n*64+j], sum);
    }
  }
}

// ---- phase C: 16 lanes per src node ----
__global__ void k_coordC(const int2* __restrict__ sd,
                         const int* __restrict__ roff_src, const int* __restrict__ slist,
                         const float* __restrict__ wvs, const float* __restrict__ x,
                         float* __restrict__ cacc){
  int tid=threadIdx.x;
  int grp=tid>>4, sub=tid&15;
  int n = blockIdx.x*16 + grp;
  if (n >= NN) return;
  int s = roff_src[n], e2 = roff_src[n+1];
  float xs0=x[n*3+0], xs1=x[n*3+1], xs2=x[n*3+2];
  float a0=0.f, a1=0.f, a2=0.f;
  for (int p=s+sub; p<e2; p+=16){
    int q = slist[p];
    float w = wvs[q];
    int d = sd[q].y;
    a0 += (xs0 - x[d*3+0])*w;
    a1 += (xs1 - x[d*3+1])*w;
    a2 += (xs2 - x[d*3+2])*w;
  }
  #pragma unroll
  for(int off=1; off<16; off<<=1){
    a0 += __shfl_xor(a0, off);
    a1 += __shfl_xor(a1, off);
    a2 += __shfl_xor(a2, off);
  }
  if (sub==0){
    cacc[n*3+0]=a0; cacc[n*3+1]=a1; cacc[n*3+2]=a2;
  }
}

// ==== tiled k_node ====
__global__ void __launch_bounds__(256)
k_node(const float* __restrict__ agg, const float* __restrict__ cacc,
       const float* __restrict__ cntinv,
       const float* __restrict__ hw1, const float* __restrict__ hb1,
       const float* __restrict__ hw2, const float* __restrict__ hb2,
       const float* __restrict__ lng, const float* __restrict__ lnb,
       float* __restrict__ h, float* __restrict__ x){
  __shared__ float cat[32][193];
  __shared__ float t1[32][129];
  __shared__ float wt[16][136];
  __shared__ float psA[32][8], psB[32][8];
  __shared__ float mu_s[32], rs_s[32];
  int tid=threadIdx.x;
  int g0=blockIdx.x*32;
  int ty=tid>>4, tx=tid&15;
  int n0=ty*2, n1=ty*2+1;
  int c8=tx*8;
  { int n=tid>>3, c0=(tid&7)*16;
    int gn=g0+n; if(gn>=NN) gn=NN-1;
    float ci = cntinv[gn];
    const float* src=h+(size_t)gn*128+c0;
    #pragma unroll
    for(int q=0;q<4;q++){
      float4 v=*(const float4*)(src+q*4);
      cat[n][c0+q*4]=v.x; cat[n][c0+q*4+1]=v.y; cat[n][c0+q*4+2]=v.z; cat[n][c0+q*4+3]=v.w;
    }
    int ca=(tid&7)*8;
    const float* srca=agg+(size_t)gn*64+ca;
    #pragma unroll
    for(int q=0;q<2;q++){
      float4 v=*(const float4*)(srca+q*4);
      cat[n][128+ca+q*4]=v.x*ci; cat[n][128+ca+q*4+1]=v.y*ci;
      cat[n][128+ca+q*4+2]=v.z*ci; cat[n][128+ca+q*4+3]=v.w*ci;
    } }
  float4 a00=*(const float4*)(hb1+c8), a01=*(const float4*)(hb1+c8+4);
  float4 a10=a00, a11=a01;
  for(int kt=0;kt<12;kt++){
    { const float* src=hw1+(size_t)(kt*16+ty)*128+c8;
      *(float4*)&wt[ty][c8]  =*(const float4*)src;
      *(float4*)&wt[ty][c8+4]=*(const float4*)(src+4); }
    __syncthreads();
    #pragma unroll
    for(int kk=0;kk<16;kk++){
      int k=kt*16+kk;
      float m0=cat[n0][k], m1=cat[n1][k];
      float4 wa=*(float4*)&wt[kk][c8], wb=*(float4*)&wt[kk][c8+4];
      a00.x+=m0*wa.x; a00.y+=m0*wa.y; a00.z+=m0*wa.z; a00.w+=m0*wa.w;
      a01.x+=m0*wb.x; a01.y+=m0*wb.y; a01.z+=m0*wb.z; a01.w+=m0*wb.w;
      a10.x+=m1*wa.x; a10.y+=m1*wa.y; a10.z+=m1*wa.z; a10.w+=m1*wa.w;
      a11.x+=m1*wb.x; a11.y+=m1*wb.y; a11.z+=m1*wb.z; a11.w+=m1*wb.w;
    }
    __syncthreads();
  }
  t1[n0][c8+0]=siluf(a00.x); t1[n0][c8+1]=siluf(a00.y); t1[n0][c8+2]=siluf(a00.z); t1[n0][c8+3]=siluf(a00.w);
  t1[n0][c8+4]=siluf(a01.x); t1[n0][c8+5]=siluf(a01.y); t1[n0][c8+6]=siluf(a01.z); t1[n0][c8+7]=siluf(a01.w);
  t1[n1][c8+0]=siluf(a10.x); t1[n1][c8+1]=siluf(a10.y); t1[n1][c8+2]=siluf(a10.z); t1[n1][c8+3]=siluf(a10.w);
  t1[n1][c8+4]=siluf(a11.x); t1[n1][c8+5]=siluf(a11.y); t1[n1][c8+6]=siluf(a11.z); t1[n1][c8+7]=siluf(a11.w);
  __syncthreads();
  a00=*(const float4*)(hb2+c8); a01=*(const float4*)(hb2+c8+4);
  a10=a00; a11=a01;
  for(int kt=0;kt<8;kt++){
    { const float* src=hw2+(size_t)(kt*16+ty)*128+c8;
      *(float4*)&wt[ty][c8]  =*(const float4*)src;
      *(float4*)&wt[ty][c8+4]=*(const float4*)(src+4); }
    __syncthreads();
    #pragma unroll
    for(int kk=0;kk<16;kk++){
      int k=kt*16+kk;
      float m0=t1[n0][k], m1=t1[n1][k];
      float4 wa=*(float4*)&wt[kk][c8], wb=*(float4*)&wt[kk][c8+4];
      a00.x+=m0*wa.x; a00.y+=m0*wa.y; a00.z+=m0*wa.z; a00.w+=m0*wa.w;
      a01.x+=m0*wb.x; a01.y+=m0*wb.y; a01.z+=m0*wb.z; a01.w+=m0*wb.w;
      a10.x+=m1*wa.x; a10.y+=m1*wa.y; a10.z+=m1*wa.z; a10.w+=m1*wa.w;
      a11.x+=m1*wb.x; a11.y+=m1*wb.y; a11.z+=m1*wb.z; a11.w+=m1*wb.w;
    }
    __syncthreads();
  }
  cat[n0][c8+0]+=a00.x; cat[n0][c8+1]+=a00.y; cat[n0][c8+2]+=a00.z; cat[n0][c8+3]+=a00.w;
  cat[n0][c8+4]+=a01.x; cat[n0][c8+5]+=a01.y; cat[n0][c8+6]+=a01.z; cat[n0][c8+7]+=a01.w;
  cat[n1][c8+0]+=a10.x; cat[n1][c8+1]+=a10.y; cat[n1][c8+2]+=a10.z; cat[n1][c8+3]+=a10.w;
  cat[n1][c8+4]+=a11.x; cat[n1][c8+5]+=a11.y; cat[n1][c8+6]+=a11.z; cat[n1][c8+7]+=a11.w;
  __syncthreads();
  { int rid=tid>>3, sub=tid&7;
    float sm=0.f, ss=0.f;
    #pragma unroll
    for(int i=0;i<16;i++){ float v=cat[rid][sub*16+i]; sm+=v; ss+=v*v; }
    psA[rid][sub]=sm; psB[rid][sub]=ss; }
  __syncthreads();
  { int rid=tid>>3, sub=tid&7;
    if(sub==0){
      float sm=0.f, ss=0.f;
      #pragma unroll
      for(int i=0;i<8;i++){ sm+=psA[rid][i]; ss+=psB[rid][i]; }
      float mu=sm*(1.0f/128.0f);
      float var=ss*(1.0f/128.0f)-mu*mu;
      mu_s[rid]=mu; rs_s[rid]=rsqrtf(fmaxf(var,0.0f)+1e-5f);
    } }
  __syncthreads();
  { int rid=tid>>3, sub=tid&7;
    int gn=g0+rid;
    if(gn<NN){
      float mu=mu_s[rid], rs=rs_s[rid];
      int c0=sub*16;
      #pragma unroll
      for(int q=0;q<4;q++){
        float4 g4=*(const float4*)(lng+c0+q*4);
        float4 b4=*(const float4*)(lnb+c0+q*4);
        float4 o;
        o.x=(cat[rid][c0+q*4+0]-mu)*rs*g4.x+b4.x;
        o.y=(cat[rid][c0+q*4+1]-mu)*rs*g4.y+b4.y;
        o.z=(cat[rid][c0+q*4+2]-mu)*rs*g4.z+b4.z;
        o.w=(cat[rid][c0+q*4+3]-mu)*rs*g4.w+b4.w;
        *(float4*)(h+(size_t)gn*128+c0+q*4)=o;
      }
    } }
  if(tid<32){
    int gn=g0+tid;
    if(gn<NN){
      float ci=cntinv[gn];
      x[gn*3+0]+=cacc[gn*3+0]*ci;
      x[gn*3+1]+=cacc[gn*3+1]*ci;
      x[gn*3+2]+=cacc[gn*3+2]*ci;
    }
  }
}

// ---- readout ----
__device__ __forceinline__ int lowerb(const int* a, int n, int v){
  int lo=0, hi=n;
  while(lo<hi){ int mid=(lo+hi)>>1; if(a[mid]<v) lo=mid+1; else hi=mid; }
  return lo;
}

__global__ void k_readout(const int* __restrict__ batch, const float* __restrict__ h,
                          const float* __restrict__ w1, const float* __restrict__ b1,
                          const float* __restrict__ w2, const float* __restrict__ b2,
                          const float* __restrict__ w3, const float* __restrict__ b3,
                          float* __restrict__ out){
  int g = blockIdx.x;
  int wl = threadIdx.x>>6, lane = threadIdx.x&63;
  __shared__ float part[4][128];
  __shared__ float gh[128];
  __shared__ float r1[128];
  __shared__ float r2[64];
  int start = lowerb(batch, NN, g);
  int end   = lowerb(batch, NN, g+1);
  float s0=0.f, s1=0.f;
  for(int n=start+wl; n<end; n+=4){
    s0 += h[(size_t)n*128+2*lane];
    s1 += h[(size_t)n*128+2*lane+1];
  }
  part[wl][2*lane]=s0; part[wl][2*lane+1]=s1;
  __syncthreads();
  float ci = 1.0f/fmaxf((float)(end-start),1.0f);
  if(wl==0){
    gh[2*lane]   = (part[0][2*lane]+part[1][2*lane]+part[2][2*lane]+part[3][2*lane])*ci;
    gh[2*lane+1] = (part[0][2*lane+1]+part[1][2*lane+1]+part[2][2*lane+1]+part[3][2*lane+1])*ci;
  }
  __syncthreads();
  if(wl==0){
    float a0=b1[2*lane], a1=b1[2*lane+1];
    for(int k=0;k<128;k++){
      float m=gh[k];
      float2 w=((const float2*)(w1+k*128))[lane];
      a0+=m*w.x; a1+=m*w.y;
    }
    r1[2*lane]=siluf(a0); r1[2*lane+1]=siluf(a1);
  }
  __syncthreads();
  if(wl==0){
    float b=b2[lane];
    for(int k=0;k<128;k++) b += r1[k]*w2[k*64+lane];
    r2[lane]=siluf(b);
  }
  __syncthreads();
  if(wl==0 && lane<2){
    float o=b3[lane];
    for(int k=0;k<64;k++) o += r2[k]*w3[k*2+lane];
    out[g*2+lane]=o;
  }
}

extern "C" void kernel_launch(void* const* d_in, const int* in_sizes, int n_in,
                              void* d_out, int out_size, void* d_ws, size_t ws_size,
                              hipStream_t stream){
  const float* nf     = (const float*)d_in[0];
  const float* coords = (const float*)d_in[1];
  const int*   ei     = (const int*)d_in[2];
  const float* ef     = (const float*)d_in[3];
  const int*   batch  = (const int*)d_in[4];

  const float* enc_w1 = (const float*)d_in[5];
  const float* enc_b1 = (const float*)d_in[6];
  const float* enc_w2 = (const float*)d_in[7];
  const float* enc_b2 = (const float*)d_in[8];
  const float* pe_w1  = (const float*)d_in[9];
  const float* pe_b1  = (const float*)d_in[10];
  const float* pe_w2  = (const float*)d_in[11];
  const float* pe_b2  = (const float*)d_in[12];
  const float* ph_w1  = (const float*)d_in[13];
  const float* ph_b1  = (const float*)d_in[14];
  const float* ph_w2  = (const float*)d_in[15];
  const float* ph_b2  = (const float*)d_in[16];
  const float* px_w1  = (const float*)d_in[17];
  const float* px_b1  = (const float*)d_in[18];
  const float* px_w2  = (const float*)d_in[19];
  const float* px_b2  = (const float*)d_in[20];
  const float* ln_g   = (const float*)d_in[21];
  const float* ln_b   = (const float*)d_in[22];
  const float* ro_w1  = (const float*)d_in[23];
  const float* ro_b1  = (const float*)d_in[24];
  const float* ro_w2  = (const float*)d_in[25];
  const float* ro_b2  = (const float*)d_in[26];
  const float* ro_w3  = (const float*)d_in[27];
  const float* ro_b3  = (const float*)d_in[28];

  char* wsb = (char*)d_ws;
  size_t off = 0;
  auto alloc_f = [&](size_t nfl)->float*{ float* p=(float*)(wsb+off); off+=nfl*4; return p; };
  auto alloc_i = [&](size_t nin)->int*  { int*   p=(int*)(wsb+off);   off+=nin*4; return p; };

  float* h      = alloc_f((size_t)NN*128);
  float* x      = alloc_f((size_t)NN*3);
  float* agg    = alloc_f((size_t)NN*64);
  float* cacc   = alloc_f((size_t)NN*3);
  float* cntinv = alloc_f(NN);
  float* pa     = alloc_f((size_t)NN*64);
  float* pb     = alloc_f((size_t)NN*64);
  float* wvs    = alloc_f(NE);
  float* ef_s   = alloc_f((size_t)NE*16);
  int2*  sd_s   = (int2*)alloc_i((size_t)NE*2);
  int* roff_dst = alloc_i(NN+1);
  int* roff_src = alloc_i(NN+1);
  int* dlist    = alloc_i(NE);
  int* slist    = alloc_i(NE);
  int* bsum     = alloc_i(256);
  int* bbase    = alloc_i(256);
  int* cnt_dst  = alloc_i(NN);   // cnt_dst..cur_src contiguous -> one memset
  int* cnt_src  = alloc_i(NN);
  int* cur_dst  = alloc_i(NN);
  int* cur_src  = alloc_i(NN);

  hipMemsetAsync(cnt_dst, 0, (size_t)4*NN*sizeof(int), stream);
  k_degrees<<<(NE+255)/256,256,0,stream>>>(ei, cnt_dst, cnt_src);
  k_scan1<<<NB_SCAN,256,0,stream>>>(cnt_dst, roff_dst, bsum);
  k_scan2<<<1,256,0,stream>>>(bsum, bbase, roff_dst);
  k_scan3<<<NB_SCAN,256,0,stream>>>(roff_dst, bbase);
  k_scan1<<<NB_SCAN,256,0,stream>>>(cnt_src, roff_src, bsum);
  k_scan2<<<1,256,0,stream>>>(bsum, bbase, roff_src);
  k_scan3<<<NB_SCAN,256,0,stream>>>(roff_src, bbase);
  k_fill<<<(NE+255)/256,256,0,stream>>>(ei, roff_dst, roff_src, cur_dst, cur_src, dlist, slist);
  k_gather<<<(NE+255)/256,256,0,stream>>>(ei, ef, dlist, sd_s, ef_s);
  k_prep<<<(NN+255)/256,256,0,stream>>>(coords, cnt_dst, x, cntinv);
  k_encoder<<<(NN+31)/32,256,0,stream>>>(nf, enc_w1, enc_b1, enc_w2, enc_b2, h);

  int G  = (NE+EB-1)/EB;
  int G8 = ((G+7)/8)*8;

  for(int l=0;l<NL;l++){
    k_pre<<<(NN+31)/32,256,0,stream>>>(h, pe_w1+(size_t)l*273*64, pe_b1+l*64, pa, pb);
    hipMemsetAsync(agg, 0, (size_t)NN*64*sizeof(float), stream);
    k_edge2<<<G8,512,0,stream>>>(sd_s, ef_s, x, pa, pb, roff_dst,
        pe_w1+(size_t)l*273*64,
        pe_w2+(size_t)l*64*64, pe_b2+l*64,
        px_w1+(size_t)l*64*64, px_b1+l*64,
        px_w2+l*64, px_b2+l,
        agg, wvs);
    k_coordC<<<(NN+15)/16,256,0,stream>>>(sd_s, roff_src, slist, wvs, x, cacc);
    k_node<<<(NN+31)/32,256,0,stream>>>(agg, cacc, cntinv,
        ph_w1+(size_t)l*192*128, ph_b1+l*128,
        ph_w2+(size_t)l*128*128, ph_b2+l*128,
        ln_g+l*128, ln_b+l*128, h, x);
  }

  k_readout<<<NG,256,0,stream>>>(batch, h,
      ro_w1, ro_b1, ro_w2, ro_b2, ro_w3, ro_b3, (float*)d_out);
}